// Round 1
// baseline (1297.238 us; speedup 1.0000x reference)
//
#include <hip/hip_runtime.h>
#include <math.h>

#define LOG2PI 1.8378770664093453f

// Problem sizes (fixed)
#define NB 32
#define NT 1024
#define ND 512
#define NH 512
#define NX 32
#define NK 8
#define NU 2

// ---------------------------------------------------------------------------
// Wave helpers (wave64)
// ---------------------------------------------------------------------------
__device__ __forceinline__ float lse8_low(float v) {
    // LSE over the 8 lanes differing in bits 0..2 (same j group, k varies)
    float m = v;
    m = fmaxf(m, __shfl_xor(m, 1, 64));
    m = fmaxf(m, __shfl_xor(m, 2, 64));
    m = fmaxf(m, __shfl_xor(m, 4, 64));
    float s = expf(v - m);
    s += __shfl_xor(s, 1, 64);
    s += __shfl_xor(s, 2, 64);
    s += __shfl_xor(s, 4, 64);
    return m + logf(s);
}
__device__ __forceinline__ float lse8_high(float v) {
    // LSE over the 8 lanes differing in bits 3..5 (k fixed, j varies)
    float m = v;
    m = fmaxf(m, __shfl_xor(m, 8, 64));
    m = fmaxf(m, __shfl_xor(m, 16, 64));
    m = fmaxf(m, __shfl_xor(m, 32, 64));
    float s = expf(v - m);
    s += __shfl_xor(s, 8, 64);
    s += __shfl_xor(s, 16, 64);
    s += __shfl_xor(s, 32, 64);
    return m + logf(s);
}
// full-wave LSE over 8 distinct values each replicated 8x; `contrib` true on
// exactly one lane per distinct value.
__device__ __forceinline__ float wave_lse_dedup(float val, bool contrib) {
    float M = val;
#pragma unroll
    for (int m = 1; m < 64; m <<= 1) M = fmaxf(M, __shfl_xor(M, m, 64));
    float S = contrib ? expf(val - M) : 0.f;
#pragma unroll
    for (int m = 1; m < 64; m <<= 1) S += __shfl_xor(S, m, 64);
    return M + logf(S);
}

// ---------------------------------------------------------------------------
// K1: h = tanh(ys @ W1 + b1)   M=32768 N=512 K=512, f32 tiled GEMM
// ---------------------------------------------------------------------------
__global__ __launch_bounds__(256) void k_gemm_h(
    const float* __restrict__ ys, const float* __restrict__ W1,
    const float* __restrict__ b1, float* __restrict__ h)
{
    __shared__ float As[16][64];  // [k][m]
    __shared__ float Bs[16][64];  // [k][n]
    const int bm = blockIdx.y * 64;
    const int bn = blockIdx.x * 64;
    const int tid = threadIdx.x;
    const int tx = tid & 15, ty = tid >> 4;
    float acc[4][4] = {};
    for (int k0 = 0; k0 < 512; k0 += 16) {
        {
            int m = tid >> 2;
            int kk = (tid & 3) << 2;
            const float4 a = *reinterpret_cast<const float4*>(
                &ys[(size_t)(bm + m) * 512 + k0 + kk]);
            As[kk + 0][m] = a.x; As[kk + 1][m] = a.y;
            As[kk + 2][m] = a.z; As[kk + 3][m] = a.w;
        }
        {
            int kk = tid >> 4;
            int n4 = (tid & 15) << 2;
            const float4 b = *reinterpret_cast<const float4*>(
                &W1[(size_t)(k0 + kk) * 512 + bn + n4]);
            *reinterpret_cast<float4*>(&Bs[kk][n4]) = b;
        }
        __syncthreads();
#pragma unroll
        for (int k = 0; k < 16; ++k) {
            float ra[4], rb[4];
#pragma unroll
            for (int i = 0; i < 4; ++i) ra[i] = As[k][ty * 4 + i];
#pragma unroll
            for (int j = 0; j < 4; ++j) rb[j] = Bs[k][tx * 4 + j];
#pragma unroll
            for (int i = 0; i < 4; ++i)
#pragma unroll
                for (int j = 0; j < 4; ++j)
                    acc[i][j] = fmaf(ra[i], rb[j], acc[i][j]);
        }
        __syncthreads();
    }
#pragma unroll
    for (int i = 0; i < 4; ++i) {
        int row = bm + ty * 4 + i;
#pragma unroll
        for (int j = 0; j < 4; ++j) {
            int col = bn + tx * 4 + j;
            h[(size_t)row * 512 + col] = tanhf(acc[i][j] + b1[col]);
        }
    }
}

// ---------------------------------------------------------------------------
// K2: mu/lv = h @ Wmu/Wlv + b;  x = mu + exp(0.5 lv)*eps;  xent
// Block handles 16 rows. 4 waves; each wave: 64 outputs (32 mu + 32 lv) x 4 rows.
// ---------------------------------------------------------------------------
__global__ __launch_bounds__(256) void k_mulv(
    const float* __restrict__ h, const float* __restrict__ Wmu,
    const float* __restrict__ bmu, const float* __restrict__ Wlv,
    const float* __restrict__ blv, const float* __restrict__ eps,
    float* __restrict__ x, float* __restrict__ xent)
{
    __shared__ float hs[16][512];
    __shared__ float lvs[16][32];
    const int tid = threadIdx.x;
    const int rowBase = blockIdx.x * 16;
    const float4* hsrc = reinterpret_cast<const float4*>(&h[(size_t)rowBase * 512]);
    float4* hdst = reinterpret_cast<float4*>(&hs[0][0]);
#pragma unroll
    for (int i = 0; i < 8; ++i) hdst[tid + i * 256] = hsrc[tid + i * 256];
    __syncthreads();
    const int lane = tid & 63;
    const int o = lane & 31;
    const bool isMu = lane < 32;
    const int r0 = (tid >> 6) * 4;
    const float* W = isMu ? Wmu : Wlv;
    float a0 = 0.f, a1 = 0.f, a2 = 0.f, a3 = 0.f;
    for (int k = 0; k < 512; ++k) {
        float w = W[k * 32 + o];
        a0 = fmaf(hs[r0 + 0][k], w, a0);
        a1 = fmaf(hs[r0 + 1][k], w, a1);
        a2 = fmaf(hs[r0 + 2][k], w, a2);
        a3 = fmaf(hs[r0 + 3][k], w, a3);
    }
    float bv = isMu ? bmu[o] : blv[o];
    a0 += bv; a1 += bv; a2 += bv; a3 += bv;
    if (!isMu) {
        lvs[r0 + 0][o] = a0; lvs[r0 + 1][o] = a1;
        lvs[r0 + 2][o] = a2; lvs[r0 + 3][o] = a3;
    }
    __syncthreads();
    if (isMu) {
        float accs[4] = {a0, a1, a2, a3};
#pragma unroll
        for (int rr = 0; rr < 4; ++rr) {
            int row = rowBase + r0 + rr;
            float lv = lvs[r0 + rr][o];
            float e = eps[(size_t)row * 32 + o];
            x[(size_t)row * 32 + o] = accs[rr] + expf(0.5f * lv) * e;
            float term = 0.5f * (e * e + lv + LOG2PI);
            for (int m = 16; m; m >>= 1) term += __shfl_down(term, m, 32);
            if (o == 0) xent[row] = term;
        }
    }
}

// ---------------------------------------------------------------------------
// K3: log_a[b,t] = log_softmax_j( x[b,t-1] @ Wz + bz ), log_eye at t=0
// One wave per (b,t); lane = j*8+k.
// ---------------------------------------------------------------------------
__global__ __launch_bounds__(256) void k_loga(
    const float* __restrict__ x, const float* __restrict__ Wz,
    const float* __restrict__ bz, float* __restrict__ log_a)
{
    const int tid = threadIdx.x;
    const int item = blockIdx.x * 4 + (tid >> 6);  // b*NT + t
    const int lane = tid & 63;
    const int t = item & (NT - 1);
    if (t == 0) {
        int j = lane >> 3, k = lane & 7;
        log_a[(size_t)item * 64 + lane] = (j == k) ? logf(1.f + 1e-10f)
                                                   : logf(1e-10f);
        return;
    }
    const float* xr = &x[((size_t)item - 1) * 32];
    float acc = bz[lane];
#pragma unroll
    for (int e = 0; e < 32; ++e) acc = fmaf(xr[e], Wz[e * 64 + lane], acc);
    float lse = lse8_high(acc);  // LSE over j (lanes differing in bits 3..5)
    log_a[(size_t)item * 64 + lane] = acc - lse;
}

// ---------------------------------------------------------------------------
// K4: means[b,tm,k,:] = x[b,tm]@A[k] + us[b,tm+1]@Bu[k] + bx[k]
//     log_b[b,tm+1,k] = sum_x gauss_lp(x[b,tm+1,x], means, x_logvar)
// One block per (b,tm); 256 threads = (k, xo).
// ---------------------------------------------------------------------------
__global__ __launch_bounds__(256) void k_means(
    const float* __restrict__ x, const float* __restrict__ us,
    const float* __restrict__ A, const float* __restrict__ Bu,
    const float* __restrict__ bx, const float* __restrict__ x_logvar,
    float* __restrict__ means, float* __restrict__ log_b)
{
    __shared__ float xs[32];
    __shared__ float uu[2];
    const int item = blockIdx.x;          // b*1023 + tm
    const int b = item / 1023;
    const int tm = item - b * 1023;
    const int tid = threadIdx.x;
    const int k = tid >> 5, xo = tid & 31;
    if (tid < 32) xs[tid] = x[((size_t)b * NT + tm) * 32 + tid];
    if (tid < 2) uu[tid] = us[((size_t)b * NT + tm + 1) * 2 + tid];
    __syncthreads();
    float acc = bx[k * 32 + xo];
#pragma unroll
    for (int e = 0; e < 32; ++e)
        acc = fmaf(xs[e], A[((size_t)k * 32 + e) * 32 + xo], acc);
    acc = fmaf(uu[0], Bu[((size_t)k * 2 + 0) * 32 + xo], acc);
    acc = fmaf(uu[1], Bu[((size_t)k * 2 + 1) * 32 + xo], acc);
    means[((size_t)item * 8 + k) * 32 + xo] = acc;
    float xv = x[((size_t)b * NT + tm + 1) * 32 + xo];
    float lvv = x_logvar[k * 32 + xo];
    float dd = xv - acc;
    float term = -0.5f * (dd * dd * expf(-lvv) + lvv + LOG2PI);
    for (int m = 16; m; m >>= 1) term += __shfl_down(term, m, 32);
    if (xo == 0) log_b[((size_t)b * NT + tm + 1) * 8 + k] = term;
}

// K4b: log_b[b,0,k] from x0 prior
__global__ __launch_bounds__(256) void k_logb0(
    const float* __restrict__ x, const float* __restrict__ x0_mean,
    const float* __restrict__ x0_logvar, float* __restrict__ log_b)
{
    const int b = blockIdx.x;
    const int tid = threadIdx.x;
    const int k = tid >> 5, xo = tid & 31;
    float xv = x[((size_t)b * NT) * 32 + xo];
    float mm = x0_mean[k * 32 + xo];
    float lvv = x0_logvar[k * 32 + xo];
    float dd = xv - mm;
    float term = -0.5f * (dd * dd * expf(-lvv) + lvv + LOG2PI);
    for (int m = 16; m; m >>= 1) term += __shfl_down(term, m, 32);
    if (xo == 0) log_b[(size_t)b * NT * 8 + k] = term;
}

// ---------------------------------------------------------------------------
// K5: forward-backward per batch. Block = 128 threads (2 waves):
// wave0 forward scan, wave1 backward scan (independent), then gamma pass.
// Lane mapping: j = lane>>3, k = lane&7. alphas/betas in LDS (64 KB).
// ---------------------------------------------------------------------------
__global__ __launch_bounds__(128) void k_fb(
    const float* __restrict__ log_a, const float* __restrict__ log_b,
    const float* __restrict__ log_init_z,
    float* __restrict__ gamma, float* __restrict__ log_px)
{
    __shared__ float fwdS[NT][8];
    __shared__ float bwdS[NT][8];
    const int b = blockIdx.x;
    const int tid = threadIdx.x;
    const int wave = tid >> 6;
    const int lane = tid & 63;
    const int j = lane >> 3, k = lane & 7;
    const float* la = &log_a[(size_t)b * NT * 64];
    const float* lb = &log_b[(size_t)b * NT * 8];

    if (wave == 0) {
        // --- forward ---
        float liz = log_init_z[j];
        float li = liz - wave_lse_dedup(liz, k == 0);
        float aj = li + lb[j];
        float c = wave_lse_dedup(aj, k == 0);
        float alpha = aj - c;   // alpha[j] on all lanes of group j
        float csum = c;
        if (k == 0) fwdS[0][j] = alpha;
        float lav_n = la[64 + lane];
        float lbv_n = lb[8 + j];
        for (int t = 1; t < NT; ++t) {
            float lav = lav_n, lbv = lbv_n;
            int tn = (t + 1 < NT) ? t + 1 : NT - 1;
            lav_n = la[(size_t)tn * 64 + lane];
            lbv_n = lb[(size_t)tn * 8 + j];
            float alpha_k = __shfl(alpha, (lane & 7) << 3, 64);  // alpha[k]
            float v = lav + alpha_k;
            float ajv = lbv + lse8_low(v);           // a[j]
            float c2 = wave_lse_dedup(ajv, k == 0);  // LSE over j
            alpha = ajv - c2;
            csum += c2;
            if (k == 0) fwdS[t][j] = alpha;
        }
        if (lane == 0) log_px[b] = csum;
    } else {
        // --- backward ---  lane holds (j = lane>>3, kp = lane&7)
        float beta = 0.f;                      // beta[j]
        if (j == 0) bwdS[NT - 1][k] = 0.f;
        float lav_n = la[(size_t)(NT - 1) * 64 + lane];
        float lbv_n = lb[(size_t)(NT - 1) * 8 + j];
        for (int t = NT - 1; t >= 1; --t) {
            float lav = lav_n, lbv = lbv_n;
            int tn = (t - 1 >= 1) ? t - 1 : 1;
            lav_n = la[(size_t)tn * 64 + lane];
            lbv_n = lb[(size_t)tn * 8 + j];
            float v = lav + lbv + beta;            // la[j][kp] + lb[j] + beta[j]
            float bk = lse8_high(v);               // LSE over j -> b[kp]
            float c2 = wave_lse_dedup(bk, j == 0); // LSE over kp
            bk -= c2;
            if (j == 0) bwdS[t - 1][k] = bk;
            beta = __shfl(bk, lane >> 3, 64);      // beta[j] for next step
        }
    }
    __syncthreads();
    // --- gamma = softmax(fwd + bwd) ---
    for (int t = tid; t < NT; t += 128) {
        float lg[8], mx = -1e30f;
#pragma unroll
        for (int q = 0; q < 8; ++q) {
            lg[q] = fwdS[t][q] + bwdS[t][q];
            mx = fmaxf(mx, lg[q]);
        }
        float s = 0.f;
#pragma unroll
        for (int q = 0; q < 8; ++q) { lg[q] = expf(lg[q] - mx); s += lg[q]; }
        float inv = 1.f / s;
#pragma unroll
        for (int q = 0; q < 8; ++q)
            gamma[((size_t)b * NT + t) * 8 + q] = lg[q] * inv;
    }
}

// ---------------------------------------------------------------------------
// K6: x_gen = (t==0 ? x : sum_k means*gamma);  y_mean = x_gen @ C + d;
//     red[b,t] = sum_d gauss_lp(ys, y_mean, y_logvar) + xent[b,t]
// Block handles 8 consecutive t (same b). 256 threads; thread owns 2 d-cols.
// ---------------------------------------------------------------------------
__global__ __launch_bounds__(256) void k_emit(
    const float* __restrict__ ys, const float* __restrict__ x,
    const float* __restrict__ means, const float* __restrict__ gamma,
    const float* __restrict__ C, const float* __restrict__ dvec,
    const float* __restrict__ y_logvar, const float* __restrict__ xent,
    float* __restrict__ red)
{
    __shared__ float xg[8][32];
    __shared__ float gs[8][8];
    __shared__ float wsum[8][4];
    const int tid = threadIdx.x;
    const int itemBase = blockIdx.x * 8;  // b*NT + t0 (t0 multiple of 8)
    const int b = itemBase >> 10;
    const int t0 = itemBase & (NT - 1);
    if (tid < 64) {
        int it = tid >> 3, q = tid & 7;
        if (t0 + it > 0)
            gs[it][q] = gamma[((size_t)itemBase + it) * 8 + q];
    }
    __syncthreads();
    {
        int it = tid >> 5, xo = tid & 31;
        int t = t0 + it;
        float v;
        if (t == 0) {
            v = x[((size_t)itemBase + it) * 32 + xo];
        } else {
            const float* mp = &means[(((size_t)b * 1023 + (t - 1)) * 8) * 32 + xo];
            v = 0.f;
#pragma unroll
            for (int q = 0; q < 8; ++q) v = fmaf(mp[q * 32], gs[it][q], v);
        }
        xg[it][xo] = v;
    }
    __syncthreads();
    float acc[8][2] = {};
    for (int e = 0; e < 32; ++e) {
        float c0 = C[e * 512 + tid];
        float c1 = C[e * 512 + tid + 256];
#pragma unroll
        for (int it = 0; it < 8; ++it) {
            float xv = xg[it][e];
            acc[it][0] = fmaf(xv, c0, acc[it][0]);
            acc[it][1] = fmaf(xv, c1, acc[it][1]);
        }
    }
    float d0 = dvec[tid], d1 = dvec[tid + 256];
    float ylv0 = y_logvar[tid], ylv1 = y_logvar[tid + 256];
    float iv0 = expf(-ylv0), iv1 = expf(-ylv1);
    float base0 = ylv0 + LOG2PI, base1 = ylv1 + LOG2PI;
#pragma unroll
    for (int it = 0; it < 8; ++it) {
        const float* yrow = &ys[((size_t)itemBase + it) * 512];
        float df0 = yrow[tid] - (acc[it][0] + d0);
        float df1 = yrow[tid + 256] - (acc[it][1] + d1);
        float lsum = -0.5f * (df0 * df0 * iv0 + base0)
                   - 0.5f * (df1 * df1 * iv1 + base1);
#pragma unroll
        for (int m = 1; m < 64; m <<= 1) lsum += __shfl_xor(lsum, m, 64);
        if ((tid & 63) == 0) wsum[it][tid >> 6] = lsum;
    }
    __syncthreads();
    if (tid < 8)
        red[itemBase + tid] = wsum[tid][0] + wsum[tid][1] + wsum[tid][2]
                            + wsum[tid][3] + xent[itemBase + tid];
}

// ---------------------------------------------------------------------------
// K7: elbo = (sum_b log_px + sum_{b,t} red) / B
// ---------------------------------------------------------------------------
__global__ __launch_bounds__(256) void k_final(
    const float* __restrict__ red, const float* __restrict__ log_px,
    float* __restrict__ out)
{
    __shared__ float ssum[4];
    float s = 0.f;
    for (int i = threadIdx.x; i < NB * NT; i += 256) s += red[i];
    if (threadIdx.x < NB) s += log_px[threadIdx.x];
#pragma unroll
    for (int m = 1; m < 64; m <<= 1) s += __shfl_xor(s, m, 64);
    if ((threadIdx.x & 63) == 0) ssum[threadIdx.x >> 6] = s;
    __syncthreads();
    if (threadIdx.x == 0)
        out[0] = (ssum[0] + ssum[1] + ssum[2] + ssum[3]) / (float)NB;
}

// ---------------------------------------------------------------------------
extern "C" void kernel_launch(void* const* d_in, const int* in_sizes, int n_in,
                              void* d_out, int out_size, void* d_ws,
                              size_t ws_size, hipStream_t stream)
{
    const float* ys        = (const float*)d_in[0];
    const float* us        = (const float*)d_in[1];
    const float* eps       = (const float*)d_in[2];
    const float* W1        = (const float*)d_in[3];
    const float* b1        = (const float*)d_in[4];
    const float* Wmu       = (const float*)d_in[5];
    const float* bmu       = (const float*)d_in[6];
    const float* Wlv       = (const float*)d_in[7];
    const float* blv       = (const float*)d_in[8];
    const float* Wz        = (const float*)d_in[9];
    const float* bz        = (const float*)d_in[10];
    const float* A         = (const float*)d_in[11];
    const float* Bu        = (const float*)d_in[12];
    const float* bx        = (const float*)d_in[13];
    const float* x_logvar  = (const float*)d_in[14];
    const float* x0_mean   = (const float*)d_in[15];
    const float* x0_logvar = (const float*)d_in[16];
    const float* C         = (const float*)d_in[17];
    const float* dv        = (const float*)d_in[18];
    const float* y_logvar  = (const float*)d_in[19];
    const float* log_init_z= (const float*)d_in[20];
    float* out = (float*)d_out;

    float* ws = (float*)d_ws;
    float* h      = ws;                    // 32768*512   = 16,777,216
    float* x      = h + 16777216;          // 32768*32    =  1,048,576
    float* xent   = x + 1048576;           // 32768
    float* log_a  = xent + 32768;          // 32768*64    =  2,097,152
    float* log_b  = log_a + 2097152;       // 32768*8     =    262,144
    float* means  = log_b + 262144;        // 32*1023*8*32=  8,380,416
    float* gam    = means + 8380416;       // 32768*8     =    262,144
    float* log_px = gam + 262144;          // 32
    float* red    = log_px + 32;           // 32768
    // total ~110.2 MiB of d_ws

    k_gemm_h<<<dim3(8, 512), 256, 0, stream>>>(ys, W1, b1, h);
    k_mulv <<<2048, 256, 0, stream>>>(h, Wmu, bmu, Wlv, blv, eps, x, xent);
    k_loga <<<8192, 256, 0, stream>>>(x, Wz, bz, log_a);
    k_means<<<32 * 1023, 256, 0, stream>>>(x, us, A, Bu, bx, x_logvar, means, log_b);
    k_logb0<<<32, 256, 0, stream>>>(x, x0_mean, x0_logvar, log_b);
    k_fb   <<<32, 128, 0, stream>>>(log_a, log_b, log_init_z, gam, log_px);
    k_emit <<<4096, 256, 0, stream>>>(ys, x, means, gam, C, dv, y_logvar, xent, red);
    k_final<<<1, 256, 0, stream>>>(red, log_px, out);
}

// Round 2
// 620.539 us; speedup vs baseline: 2.0905x; 2.0905x over previous
//
#include <hip/hip_runtime.h>
#include <math.h>

#define LOG2PI 1.8378770664093453f

// Problem sizes (fixed)
#define NB 32
#define NT 1024
#define ND 512
#define NH 512
#define NX 32
#define NK 8
#define NU 2

typedef __attribute__((ext_vector_type(8))) short bf16x8;
typedef __attribute__((ext_vector_type(4))) float f32x4;

__device__ __forceinline__ unsigned short f2bf(float f) {
    unsigned u = __float_as_uint(f);
    unsigned r = (u + 0x7FFF + ((u >> 16) & 1)) >> 16;
    return (unsigned short)r;
}

// ---------------------------------------------------------------------------
// Wave helpers (wave64)
// ---------------------------------------------------------------------------
__device__ __forceinline__ float lse8_high(float v) {
    // LSE over the 8 lanes differing in bits 3..5 (k fixed, j varies)
    float m = v;
    m = fmaxf(m, __shfl_xor(m, 8, 64));
    m = fmaxf(m, __shfl_xor(m, 16, 64));
    m = fmaxf(m, __shfl_xor(m, 32, 64));
    float s = expf(v - m);
    s += __shfl_xor(s, 8, 64);
    s += __shfl_xor(s, 16, 64);
    s += __shfl_xor(s, 32, 64);
    return m + logf(s);
}

// ---------------------------------------------------------------------------
// Cast kernels
// ---------------------------------------------------------------------------
__global__ __launch_bounds__(256) void k_cast_ys(
    const float* __restrict__ in, unsigned short* __restrict__ out)
{
    size_t i = ((size_t)blockIdx.x * 256 + threadIdx.x) * 4;
    float4 v = *reinterpret_cast<const float4*>(&in[i]);
    ushort4 o;
    o.x = f2bf(v.x); o.y = f2bf(v.y); o.z = f2bf(v.z); o.w = f2bf(v.w);
    *reinterpret_cast<ushort4*>(&out[i]) = o;
}

// W1 [K=512][N=512] f32 -> W1T [N][K] bf16
__global__ __launch_bounds__(256) void k_castT(
    const float* __restrict__ W, unsigned short* __restrict__ WT)
{
    __shared__ float tile[32][33];
    const int bx = blockIdx.x * 32;  // k-base
    const int by = blockIdx.y * 32;  // n-base
    const int tx = threadIdx.x & 31, ty = threadIdx.x >> 5;
    for (int i = ty; i < 32; i += 8)
        tile[i][tx] = W[(size_t)(bx + i) * 512 + by + tx];
    __syncthreads();
    for (int i = ty; i < 32; i += 8)
        WT[(size_t)(by + i) * 512 + bx + tx] = f2bf(tile[tx][i]);
}

// ---------------------------------------------------------------------------
// K1: h = tanh(ys @ W1 + b1) via bf16 MFMA. A=[M,K] bf16, B=W1T=[N,K] bf16.
// 128x128 tile, BK=64, 4 waves (2x2), 4x4 16x16 frags per wave.
// LDS tiles XOR-swizzled (16B slot ^ (row&7)) to kill ds_read_b128 conflicts.
// ---------------------------------------------------------------------------
__global__ __launch_bounds__(256) void k_gemm_h_mfma(
    const unsigned short* __restrict__ Abf,  // [32768][512]
    const unsigned short* __restrict__ Bbf,  // [512][512] (=W1^T)
    const float* __restrict__ b1, float* __restrict__ h)
{
    __shared__ unsigned short As[128 * 64];
    __shared__ unsigned short Bs[128 * 64];
    const int tid = threadIdx.x;
    const int bm = blockIdx.y * 128;
    const int bn = blockIdx.x * 128;
    const int wid = tid >> 6, lane = tid & 63;
    const int wm = wid >> 1, wn = wid & 1;

    f32x4 acc[4][4];
#pragma unroll
    for (int m = 0; m < 4; ++m)
#pragma unroll
        for (int n = 0; n < 4; ++n)
            acc[m][n] = (f32x4){0.f, 0.f, 0.f, 0.f};

    for (int k0 = 0; k0 < 512; k0 += 64) {
#pragma unroll
        for (int r = 0; r < 4; ++r) {
            int l = tid + r * 256;      // 16B-unit linear index in tile
            int row = l >> 3, c8 = l & 7;
            int sidx = row * 8 + (c8 ^ (row & 7));  // swizzled 16B slot
            uint4 va = *reinterpret_cast<const uint4*>(
                &Abf[(size_t)(bm + row) * 512 + k0 + c8 * 8]);
            *reinterpret_cast<uint4*>(&As[sidx * 8]) = va;
            uint4 vb = *reinterpret_cast<const uint4*>(
                &Bbf[(size_t)(bn + row) * 512 + k0 + c8 * 8]);
            *reinterpret_cast<uint4*>(&Bs[sidx * 8]) = vb;
        }
        __syncthreads();
#pragma unroll
        for (int kh = 0; kh < 2; ++kh) {
            bf16x8 af[4], bfr[4];
            const int c8r = kh * 4 + (lane >> 4);
#pragma unroll
            for (int m = 0; m < 4; ++m) {
                int rA = wm * 64 + m * 16 + (lane & 15);
                af[m] = *reinterpret_cast<bf16x8*>(
                    &As[rA * 64 + (c8r ^ (rA & 7)) * 8]);
            }
#pragma unroll
            for (int n = 0; n < 4; ++n) {
                int rB = wn * 64 + n * 16 + (lane & 15);
                bfr[n] = *reinterpret_cast<bf16x8*>(
                    &Bs[rB * 64 + (c8r ^ (rB & 7)) * 8]);
            }
#pragma unroll
            for (int m = 0; m < 4; ++m)
#pragma unroll
                for (int n = 0; n < 4; ++n)
                    acc[m][n] = __builtin_amdgcn_mfma_f32_16x16x32_bf16(
                        af[m], bfr[n], acc[m][n], 0, 0, 0);
        }
        __syncthreads();
    }
    // epilogue
    float b1v[4];
#pragma unroll
    for (int n = 0; n < 4; ++n)
        b1v[n] = b1[bn + wn * 64 + n * 16 + (lane & 15)];
#pragma unroll
    for (int m = 0; m < 4; ++m) {
#pragma unroll
        for (int q = 0; q < 4; ++q) {
            int row = bm + wm * 64 + m * 16 + (lane >> 4) * 4 + q;
#pragma unroll
            for (int n = 0; n < 4; ++n) {
                int col = bn + wn * 64 + n * 16 + (lane & 15);
                h[(size_t)row * 512 + col] = tanhf(acc[m][n][q] + b1v[n]);
            }
        }
    }
}

// ---------------------------------------------------------------------------
// K2: mu/lv = h @ Wmu/Wlv + b;  x = mu + exp(0.5 lv)*eps;  xent
// ---------------------------------------------------------------------------
__global__ __launch_bounds__(256) void k_mulv(
    const float* __restrict__ h, const float* __restrict__ Wmu,
    const float* __restrict__ bmu, const float* __restrict__ Wlv,
    const float* __restrict__ blv, const float* __restrict__ eps,
    float* __restrict__ x, float* __restrict__ xent)
{
    __shared__ float hs[16][512];
    __shared__ float lvs[16][32];
    const int tid = threadIdx.x;
    const int rowBase = blockIdx.x * 16;
    const float4* hsrc = reinterpret_cast<const float4*>(&h[(size_t)rowBase * 512]);
    float4* hdst = reinterpret_cast<float4*>(&hs[0][0]);
#pragma unroll
    for (int i = 0; i < 8; ++i) hdst[tid + i * 256] = hsrc[tid + i * 256];
    __syncthreads();
    const int lane = tid & 63;
    const int o = lane & 31;
    const bool isMu = lane < 32;
    const int r0 = (tid >> 6) * 4;
    const float* W = isMu ? Wmu : Wlv;
    float a0 = 0.f, a1 = 0.f, a2 = 0.f, a3 = 0.f;
    for (int k = 0; k < 512; ++k) {
        float w = W[k * 32 + o];
        a0 = fmaf(hs[r0 + 0][k], w, a0);
        a1 = fmaf(hs[r0 + 1][k], w, a1);
        a2 = fmaf(hs[r0 + 2][k], w, a2);
        a3 = fmaf(hs[r0 + 3][k], w, a3);
    }
    float bv = isMu ? bmu[o] : blv[o];
    a0 += bv; a1 += bv; a2 += bv; a3 += bv;
    if (!isMu) {
        lvs[r0 + 0][o] = a0; lvs[r0 + 1][o] = a1;
        lvs[r0 + 2][o] = a2; lvs[r0 + 3][o] = a3;
    }
    __syncthreads();
    if (isMu) {
        float accs[4] = {a0, a1, a2, a3};
#pragma unroll
        for (int rr = 0; rr < 4; ++rr) {
            int row = rowBase + r0 + rr;
            float lv = lvs[r0 + rr][o];
            float e = eps[(size_t)row * 32 + o];
            x[(size_t)row * 32 + o] = accs[rr] + expf(0.5f * lv) * e;
            float term = 0.5f * (e * e + lv + LOG2PI);
            for (int m = 16; m; m >>= 1) term += __shfl_down(term, m, 32);
            if (o == 0) xent[row] = term;
        }
    }
}

// ---------------------------------------------------------------------------
// K3: a[b,t] = softmax_j( x[b,t-1] @ Wz + bz )  (LINEAR probs; t=0 unused)
// ---------------------------------------------------------------------------
__global__ __launch_bounds__(256) void k_loga(
    const float* __restrict__ x, const float* __restrict__ Wz,
    const float* __restrict__ bz, float* __restrict__ a_lin)
{
    const int tid = threadIdx.x;
    const int item = blockIdx.x * 4 + (tid >> 6);  // b*NT + t
    const int lane = tid & 63;
    const int t = item & (NT - 1);
    if (t == 0) return;  // never consumed
    const float* xr = &x[((size_t)item - 1) * 32];
    float acc = bz[lane];
#pragma unroll
    for (int e = 0; e < 32; ++e) acc = fmaf(xr[e], Wz[e * 64 + lane], acc);
    float lse = lse8_high(acc);  // LSE over j
    a_lin[(size_t)item * 64 + lane] = expf(acc - lse);
}

// ---------------------------------------------------------------------------
// K4: means + log_b (unchanged)
// ---------------------------------------------------------------------------
__global__ __launch_bounds__(256) void k_means(
    const float* __restrict__ x, const float* __restrict__ us,
    const float* __restrict__ A, const float* __restrict__ Bu,
    const float* __restrict__ bx, const float* __restrict__ x_logvar,
    float* __restrict__ means, float* __restrict__ log_b)
{
    __shared__ float xs[32];
    __shared__ float uu[2];
    const int item = blockIdx.x;          // b*1023 + tm
    const int b = item / 1023;
    const int tm = item - b * 1023;
    const int tid = threadIdx.x;
    const int k = tid >> 5, xo = tid & 31;
    if (tid < 32) xs[tid] = x[((size_t)b * NT + tm) * 32 + tid];
    if (tid < 2) uu[tid] = us[((size_t)b * NT + tm + 1) * 2 + tid];
    __syncthreads();
    float acc = bx[k * 32 + xo];
#pragma unroll
    for (int e = 0; e < 32; ++e)
        acc = fmaf(xs[e], A[((size_t)k * 32 + e) * 32 + xo], acc);
    acc = fmaf(uu[0], Bu[((size_t)k * 2 + 0) * 32 + xo], acc);
    acc = fmaf(uu[1], Bu[((size_t)k * 2 + 1) * 32 + xo], acc);
    means[((size_t)item * 8 + k) * 32 + xo] = acc;
    float xv = x[((size_t)b * NT + tm + 1) * 32 + xo];
    float lvv = x_logvar[k * 32 + xo];
    float dd = xv - acc;
    float term = -0.5f * (dd * dd * expf(-lvv) + lvv + LOG2PI);
    for (int m = 16; m; m >>= 1) term += __shfl_down(term, m, 32);
    if (xo == 0) log_b[((size_t)b * NT + tm + 1) * 8 + k] = term;
}

__global__ __launch_bounds__(256) void k_logb0(
    const float* __restrict__ x, const float* __restrict__ x0_mean,
    const float* __restrict__ x0_logvar, float* __restrict__ log_b)
{
    const int b = blockIdx.x;
    const int tid = threadIdx.x;
    const int k = tid >> 5, xo = tid & 31;
    float xv = x[((size_t)b * NT) * 32 + xo];
    float mm = x0_mean[k * 32 + xo];
    float lvv = x0_logvar[k * 32 + xo];
    float dd = xv - mm;
    float term = -0.5f * (dd * dd * expf(-lvv) + lvv + LOG2PI);
    for (int m = 16; m; m >>= 1) term += __shfl_down(term, m, 32);
    if (xo == 0) log_b[(size_t)b * NT * 8 + k] = term;
}

// ---------------------------------------------------------------------------
// K5: forward-backward, scaled LINEAR space. lane = j*8+k.
// alpha/beta unnormalized (per-t scale arbitrary; gamma normalizes).
// Renormalize every 4 steps. log_px = sum(mb) + sum(log renorm) + log(final).
// Ring-buffer prefetch depth 8; exp/max of log_b precomputed at refill.
// ---------------------------------------------------------------------------
__global__ __launch_bounds__(128) void k_fb(
    const float* __restrict__ a_lin, const float* __restrict__ log_b,
    const float* __restrict__ log_init_z,
    float* __restrict__ gamma, float* __restrict__ log_px)
{
    __shared__ float fwdS[NT][8];
    __shared__ float bwdS[NT][8];
    const int b = blockIdx.x;
    const int tid = threadIdx.x;
    const int wave = tid >> 6;
    const int lane = tid & 63;
    const int j = lane >> 3;
    const int k = lane & 7;
    const float* la = &a_lin[(size_t)b * NT * 64];
    const float* lb = &log_b[(size_t)b * NT * 8];

    float aR[8], beR[8], mbR[8];

    if (wave == 0) {
        // ---- forward ----
        float liz = log_init_z[j];
        float mz = liz;
        mz = fmaxf(mz, __shfl_xor(mz, 8, 64));
        mz = fmaxf(mz, __shfl_xor(mz, 16, 64));
        mz = fmaxf(mz, __shfl_xor(mz, 32, 64));
        float sz = expf(liz - mz);
        sz += __shfl_xor(sz, 8, 64);
        sz += __shfl_xor(sz, 16, 64);
        sz += __shfl_xor(sz, 32, 64);
        float pi = expf(liz - mz) / sz;

        float lb0 = lb[j];
        float mb0 = lb0;
        mb0 = fmaxf(mb0, __shfl_xor(mb0, 8, 64));
        mb0 = fmaxf(mb0, __shfl_xor(mb0, 16, 64));
        mb0 = fmaxf(mb0, __shfl_xor(mb0, 32, 64));
        float alpha = pi * expf(lb0 - mb0);   // j-indexed, replicated over k
        float mbsum = mb0;
        float logS = 0.f;
        if (k == 0) fwdS[0][j] = alpha;

        // preload ring: t = 1..8
#pragma unroll
        for (int r = 0; r < 8; ++r) {
            int tc = 1 + r;
            aR[r] = la[(size_t)tc * 64 + lane];
            float lbn = lb[(size_t)tc * 8 + j];
            float mm = lbn;
            mm = fmaxf(mm, __shfl_xor(mm, 8, 64));
            mm = fmaxf(mm, __shfl_xor(mm, 16, 64));
            mm = fmaxf(mm, __shfl_xor(mm, 32, 64));
            beR[r] = expf(lbn - mm);
            mbR[r] = mm;
        }

        for (int tb = 1; tb <= 1009; tb += 8) {
#pragma unroll
            for (int r = 0; r < 8; ++r) {
                const int t = tb + r;
                float av = aR[r];
                float bexp = beR[r];
                mbsum += mbR[r];
                // refill slot with t+8 (off critical chain)
                {
                    int tf = t + 8;
                    int tc = tf < NT ? tf : NT - 1;
                    aR[r] = la[(size_t)tc * 64 + lane];
                    float lbn = lb[(size_t)tc * 8 + j];
                    float mm = lbn;
                    mm = fmaxf(mm, __shfl_xor(mm, 8, 64));
                    mm = fmaxf(mm, __shfl_xor(mm, 16, 64));
                    mm = fmaxf(mm, __shfl_xor(mm, 32, 64));
                    beR[r] = expf(lbn - mm);
                    mbR[r] = mm;
                }
                // critical chain
                float alpha_k = __shfl(alpha, (lane & 7) << 3, 64);
                float v = av * alpha_k;
                v += __shfl_xor(v, 1, 64);
                v += __shfl_xor(v, 2, 64);
                v += __shfl_xor(v, 4, 64);
                alpha = v * bexp;             // j-indexed
                if (k == 0) fwdS[t][j] = alpha;
                if (r == 2 || r == 6) {       // t&3==3
                    float s = alpha;
                    s += __shfl_xor(s, 8, 64);
                    s += __shfl_xor(s, 16, 64);
                    s += __shfl_xor(s, 32, 64);
                    logS += logf(s);
                    alpha *= (1.f / s);
                }
            }
        }
        // tail t = 1017..1023 using ring slots 0..6
#pragma unroll
        for (int r = 0; r < 7; ++r) {
            const int t = 1017 + r;
            float av = aR[r];
            float bexp = beR[r];
            mbsum += mbR[r];
            float alpha_k = __shfl(alpha, (lane & 7) << 3, 64);
            float v = av * alpha_k;
            v += __shfl_xor(v, 1, 64);
            v += __shfl_xor(v, 2, 64);
            v += __shfl_xor(v, 4, 64);
            alpha = v * bexp;
            if (k == 0) fwdS[t][j] = alpha;
            if (r == 2 || r == 6) {
                float s = alpha;
                s += __shfl_xor(s, 8, 64);
                s += __shfl_xor(s, 16, 64);
                s += __shfl_xor(s, 32, 64);
                logS += logf(s);
                alpha *= (1.f / s);
            }
        }
        float s = alpha;
        s += __shfl_xor(s, 8, 64);
        s += __shfl_xor(s, 16, 64);
        s += __shfl_xor(s, 32, 64);
        if (lane == 0) log_px[b] = mbsum + logS + logf(s);
    } else {
        // ---- backward ----
        float beta = 1.f;                     // j-indexed, replicated
        if (j == 0) bwdS[NT - 1][k] = 1.f;
        // preload ring: t = 1023-r
#pragma unroll
        for (int r = 0; r < 8; ++r) {
            int tc = 1023 - r;
            aR[r] = la[(size_t)tc * 64 + lane];
            float lbn = lb[(size_t)tc * 8 + j];
            float mm = lbn;
            mm = fmaxf(mm, __shfl_xor(mm, 8, 64));
            mm = fmaxf(mm, __shfl_xor(mm, 16, 64));
            mm = fmaxf(mm, __shfl_xor(mm, 32, 64));
            beR[r] = expf(lbn - mm);
            mbR[r] = mm;
        }
        for (int tb = 1023; tb >= 15; tb -= 8) {
#pragma unroll
            for (int r = 0; r < 8; ++r) {
                const int t = tb - r;
                float av = aR[r];
                float bexp = beR[r];
                {
                    int tf = t - 8;
                    int tc = tf >= 1 ? tf : 1;
                    aR[r] = la[(size_t)tc * 64 + lane];
                    float lbn = lb[(size_t)tc * 8 + j];
                    float mm = lbn;
                    mm = fmaxf(mm, __shfl_xor(mm, 8, 64));
                    mm = fmaxf(mm, __shfl_xor(mm, 16, 64));
                    mm = fmaxf(mm, __shfl_xor(mm, 32, 64));
                    beR[r] = expf(lbn - mm);
                }
                float g = bexp * beta;        // j-indexed
                float v = av * g;
                v += __shfl_xor(v, 8, 64);
                v += __shfl_xor(v, 16, 64);
                v += __shfl_xor(v, 32, 64);   // k-indexed, replicated over j
                if (r == 3 || r == 7) {       // t&3==0
                    float s = v;
                    s += __shfl_xor(s, 1, 64);
                    s += __shfl_xor(s, 2, 64);
                    s += __shfl_xor(s, 4, 64);
                    v *= (1.f / s);
                }
                if (lane < 8) bwdS[t - 1][lane] = v;
                beta = __shfl(v, lane >> 3, 64);
            }
        }
        // tail t = 7..1 using ring slots 0..6
#pragma unroll
        for (int r = 0; r < 7; ++r) {
            const int t = 7 - r;
            float av = aR[r];
            float bexp = beR[r];
            float g = bexp * beta;
            float v = av * g;
            v += __shfl_xor(v, 8, 64);
            v += __shfl_xor(v, 16, 64);
            v += __shfl_xor(v, 32, 64);
            if (r == 3) {
                float s = v;
                s += __shfl_xor(s, 1, 64);
                s += __shfl_xor(s, 2, 64);
                s += __shfl_xor(s, 4, 64);
                v *= (1.f / s);
            }
            if (lane < 8) bwdS[t - 1][lane] = v;
            beta = __shfl(v, lane >> 3, 64);
        }
    }
    __syncthreads();
    // gamma = fwd*bwd / sum  (linear)
    for (int t = tid; t < NT; t += 128) {
        float lg[8], s = 0.f;
#pragma unroll
        for (int q = 0; q < 8; ++q) {
            lg[q] = fwdS[t][q] * bwdS[t][q];
            s += lg[q];
        }
        float inv = 1.f / s;
#pragma unroll
        for (int q = 0; q < 8; ++q)
            gamma[((size_t)b * NT + t) * 8 + q] = lg[q] * inv;
    }
}

// ---------------------------------------------------------------------------
// K6: emission + reduction (unchanged)
// ---------------------------------------------------------------------------
__global__ __launch_bounds__(256) void k_emit(
    const float* __restrict__ ys, const float* __restrict__ x,
    const float* __restrict__ means, const float* __restrict__ gamma,
    const float* __restrict__ C, const float* __restrict__ dvec,
    const float* __restrict__ y_logvar, const float* __restrict__ xent,
    float* __restrict__ red)
{
    __shared__ float xg[8][32];
    __shared__ float gs[8][8];
    __shared__ float wsum[8][4];
    const int tid = threadIdx.x;
    const int itemBase = blockIdx.x * 8;
    const int b = itemBase >> 10;
    const int t0 = itemBase & (NT - 1);
    if (tid < 64) {
        int it = tid >> 3, q = tid & 7;
        if (t0 + it > 0)
            gs[it][q] = gamma[((size_t)itemBase + it) * 8 + q];
    }
    __syncthreads();
    {
        int it = tid >> 5, xo = tid & 31;
        int t = t0 + it;
        float v;
        if (t == 0) {
            v = x[((size_t)itemBase + it) * 32 + xo];
        } else {
            const float* mp = &means[(((size_t)b * 1023 + (t - 1)) * 8) * 32 + xo];
            v = 0.f;
#pragma unroll
            for (int q = 0; q < 8; ++q) v = fmaf(mp[q * 32], gs[it][q], v);
        }
        xg[it][xo] = v;
    }
    __syncthreads();
    float acc[8][2] = {};
    for (int e = 0; e < 32; ++e) {
        float c0 = C[e * 512 + tid];
        float c1 = C[e * 512 + tid + 256];
#pragma unroll
        for (int it = 0; it < 8; ++it) {
            float xv = xg[it][e];
            acc[it][0] = fmaf(xv, c0, acc[it][0]);
            acc[it][1] = fmaf(xv, c1, acc[it][1]);
        }
    }
    float d0 = dvec[tid], d1 = dvec[tid + 256];
    float ylv0 = y_logvar[tid], ylv1 = y_logvar[tid + 256];
    float iv0 = expf(-ylv0), iv1 = expf(-ylv1);
    float base0 = ylv0 + LOG2PI, base1 = ylv1 + LOG2PI;
#pragma unroll
    for (int it = 0; it < 8; ++it) {
        const float* yrow = &ys[((size_t)itemBase + it) * 512];
        float df0 = yrow[tid] - (acc[it][0] + d0);
        float df1 = yrow[tid + 256] - (acc[it][1] + d1);
        float lsum = -0.5f * (df0 * df0 * iv0 + base0)
                   - 0.5f * (df1 * df1 * iv1 + base1);
#pragma unroll
        for (int m = 1; m < 64; m <<= 1) lsum += __shfl_xor(lsum, m, 64);
        if ((tid & 63) == 0) wsum[it][tid >> 6] = lsum;
    }
    __syncthreads();
    if (tid < 8)
        red[itemBase + tid] = wsum[tid][0] + wsum[tid][1] + wsum[tid][2]
                            + wsum[tid][3] + xent[itemBase + tid];
}

__global__ __launch_bounds__(256) void k_final(
    const float* __restrict__ red, const float* __restrict__ log_px,
    float* __restrict__ out)
{
    __shared__ float ssum[4];
    float s = 0.f;
    for (int i = threadIdx.x; i < NB * NT; i += 256) s += red[i];
    if (threadIdx.x < NB) s += log_px[threadIdx.x];
#pragma unroll
    for (int m = 1; m < 64; m <<= 1) s += __shfl_xor(s, m, 64);
    if ((threadIdx.x & 63) == 0) ssum[threadIdx.x >> 6] = s;
    __syncthreads();
    if (threadIdx.x == 0)
        out[0] = (ssum[0] + ssum[1] + ssum[2] + ssum[3]) / (float)NB;
}

// ---------------------------------------------------------------------------
extern "C" void kernel_launch(void* const* d_in, const int* in_sizes, int n_in,
                              void* d_out, int out_size, void* d_ws,
                              size_t ws_size, hipStream_t stream)
{
    const float* ys        = (const float*)d_in[0];
    const float* us        = (const float*)d_in[1];
    const float* eps       = (const float*)d_in[2];
    const float* W1        = (const float*)d_in[3];
    const float* b1        = (const float*)d_in[4];
    const float* Wmu       = (const float*)d_in[5];
    const float* bmu       = (const float*)d_in[6];
    const float* Wlv       = (const float*)d_in[7];
    const float* blv       = (const float*)d_in[8];
    const float* Wz        = (const float*)d_in[9];
    const float* bz        = (const float*)d_in[10];
    const float* A         = (const float*)d_in[11];
    const float* Bu        = (const float*)d_in[12];
    const float* bx        = (const float*)d_in[13];
    const float* x_logvar  = (const float*)d_in[14];
    const float* x0_mean   = (const float*)d_in[15];
    const float* x0_logvar = (const float*)d_in[16];
    const float* C         = (const float*)d_in[17];
    const float* dv        = (const float*)d_in[18];
    const float* y_logvar  = (const float*)d_in[19];
    const float* log_init_z= (const float*)d_in[20];
    float* out = (float*)d_out;

    float* ws = (float*)d_ws;
    float* h      = ws;                    // 16,777,216 f32
    float* x      = h + 16777216;          // 1,048,576
    float* xent   = x + 1048576;           // 32,768
    float* a_lin  = xent + 32768;          // 2,097,152
    float* log_b  = a_lin + 2097152;       // 262,144
    float* means  = log_b + 262144;        // 8,380,416
    float* gam    = means + 8380416;       // 262,144
    float* log_px = gam + 262144;          // 32
    float* red    = log_px + 32;           // 32,768

    // Transient bf16 buffers, aliased over regions written only AFTER the GEMM:
    // ysb (33.55 MB) over x..means (all post-GEMM writes); w1t (0.5 MB) over gam.
    unsigned short* ysb = (unsigned short*)x;
    unsigned short* w1t = (unsigned short*)gam;

    k_cast_ys<<<16384, 256, 0, stream>>>(ys, ysb);
    k_castT  <<<dim3(16, 16), 256, 0, stream>>>(W1, w1t);
    k_gemm_h_mfma<<<dim3(4, 256), 256, 0, stream>>>(ysb, w1t, b1, h);
    k_mulv <<<2048, 256, 0, stream>>>(h, Wmu, bmu, Wlv, blv, eps, x, xent);
    k_loga <<<8192, 256, 0, stream>>>(x, Wz, bz, a_lin);
    k_means<<<32 * 1023, 256, 0, stream>>>(x, us, A, Bu, bx, x_logvar, means, log_b);
    k_logb0<<<32, 256, 0, stream>>>(x, x0_mean, x0_logvar, log_b);
    k_fb   <<<32, 128, 0, stream>>>(a_lin, log_b, log_init_z, gam, log_px);
    k_emit <<<4096, 256, 0, stream>>>(ys, x, means, gam, C, dv, y_logvar, xent, red);
    k_final<<<1, 256, 0, stream>>>(red, log_px, out);
}

// Round 3
// 487.089 us; speedup vs baseline: 2.6632x; 1.2740x over previous
//
#include <hip/hip_runtime.h>
#include <math.h>

#define LOG2PI 1.8378770664093453f

// Problem sizes (fixed)
#define NB 32
#define NT 1024
#define ND 512
#define NH 512
#define NX 32
#define NK 8
#define NU 2

typedef __attribute__((ext_vector_type(8))) short bf16x8;
typedef __attribute__((ext_vector_type(4))) float f32x4;

__device__ __forceinline__ unsigned short f2bf(float f) {
    unsigned u = __float_as_uint(f);
    unsigned r = (u + 0x7FFF + ((u >> 16) & 1)) >> 16;
    return (unsigned short)r;
}

// ds_swizzle xor within 32-lane halves (masks <=7 stay within 8-groups)
template <int M>
__device__ __forceinline__ float swzx(float v) {
    return __int_as_float(
        __builtin_amdgcn_ds_swizzle(__float_as_int(v), (M << 10) | 0x1F));
}

__device__ __forceinline__ float lse8_high(float v) {
    float m = v;
    m = fmaxf(m, __shfl_xor(m, 8, 64));
    m = fmaxf(m, __shfl_xor(m, 16, 64));
    m = fmaxf(m, __shfl_xor(m, 32, 64));
    float s = expf(v - m);
    s += __shfl_xor(s, 8, 64);
    s += __shfl_xor(s, 16, 64);
    s += __shfl_xor(s, 32, 64);
    return m + logf(s);
}

// ---------------------------------------------------------------------------
// W1 [K=512][N=512] f32 -> W1T [N][K] bf16
// ---------------------------------------------------------------------------
__global__ __launch_bounds__(256) void k_castT(
    const float* __restrict__ W, unsigned short* __restrict__ WT)
{
    __shared__ float tile[32][33];
    const int bx = blockIdx.x * 32;  // k-base
    const int by = blockIdx.y * 32;  // n-base
    const int tx = threadIdx.x & 31, ty = threadIdx.x >> 5;
    for (int i = ty; i < 32; i += 8)
        tile[i][tx] = W[(size_t)(bx + i) * 512 + by + tx];
    __syncthreads();
    for (int i = ty; i < 32; i += 8)
        WT[(size_t)(by + i) * 512 + bx + tx] = f2bf(tile[tx][i]);
}

// Wmu/Wlv [512][32] f32 -> out [64][512] bf16 (rows 0-31 mu^T, 32-63 lv^T)
__global__ __launch_bounds__(256) void k_cast_mulv(
    const float* __restrict__ Wmu, const float* __restrict__ Wlv,
    unsigned short* __restrict__ out)
{
    __shared__ float tile[32][33];
    const float* W = blockIdx.y ? Wlv : Wmu;
    const int base = blockIdx.y * 32;
    const int g = blockIdx.x;  // k-chunk
    const int tx = threadIdx.x & 31, ty = threadIdx.x >> 5;
    for (int i = ty; i < 32; i += 8)
        tile[i][tx] = W[(size_t)(g * 32 + i) * 32 + tx];  // [kk][o]
    __syncthreads();
    for (int i = ty; i < 32; i += 8)
        out[(size_t)(base + i) * 512 + g * 32 + tx] = f2bf(tile[tx][i]);
}

// ---------------------------------------------------------------------------
// K1: h_bf = bf16(tanh(ys @ W1 + b1)). Reads f32 ys, casts in-register.
// 128x128 tile, BK=64, 4 waves, XOR-swizzled LDS.
// ---------------------------------------------------------------------------
__global__ __launch_bounds__(256) void k_gemm_h_mfma(
    const float* __restrict__ ys,            // [32768][512] f32
    const unsigned short* __restrict__ Bbf,  // [512][512] bf16 (=W1^T)
    const float* __restrict__ b1, unsigned short* __restrict__ hb)
{
    __shared__ unsigned short As[128 * 64];
    __shared__ unsigned short Bs[128 * 64];
    const int tid = threadIdx.x;
    const int bm = blockIdx.y * 128;
    const int bn = blockIdx.x * 128;
    const int wid = tid >> 6, lane = tid & 63;
    const int wm = wid >> 1, wn = wid & 1;

    f32x4 acc[4][4];
#pragma unroll
    for (int m = 0; m < 4; ++m)
#pragma unroll
        for (int n = 0; n < 4; ++n)
            acc[m][n] = (f32x4){0.f, 0.f, 0.f, 0.f};

    for (int k0 = 0; k0 < 512; k0 += 64) {
#pragma unroll
        for (int r = 0; r < 4; ++r) {
            int l = tid + r * 256;
            int row = l >> 3, c8 = l & 7;
            int sidx = row * 8 + (c8 ^ (row & 7));
            const float4 f0 = *reinterpret_cast<const float4*>(
                &ys[(size_t)(bm + row) * 512 + k0 + c8 * 8]);
            const float4 f1 = *reinterpret_cast<const float4*>(
                &ys[(size_t)(bm + row) * 512 + k0 + c8 * 8 + 4]);
            uint4 ua;
            ua.x = (unsigned)f2bf(f0.x) | ((unsigned)f2bf(f0.y) << 16);
            ua.y = (unsigned)f2bf(f0.z) | ((unsigned)f2bf(f0.w) << 16);
            ua.z = (unsigned)f2bf(f1.x) | ((unsigned)f2bf(f1.y) << 16);
            ua.w = (unsigned)f2bf(f1.z) | ((unsigned)f2bf(f1.w) << 16);
            *reinterpret_cast<uint4*>(&As[sidx * 8]) = ua;
            uint4 vb = *reinterpret_cast<const uint4*>(
                &Bbf[(size_t)(bn + row) * 512 + k0 + c8 * 8]);
            *reinterpret_cast<uint4*>(&Bs[sidx * 8]) = vb;
        }
        __syncthreads();
#pragma unroll
        for (int kh = 0; kh < 2; ++kh) {
            bf16x8 af[4], bfr[4];
            const int c8r = kh * 4 + (lane >> 4);
#pragma unroll
            for (int m = 0; m < 4; ++m) {
                int rA = wm * 64 + m * 16 + (lane & 15);
                af[m] = *reinterpret_cast<bf16x8*>(
                    &As[rA * 64 + (c8r ^ (rA & 7)) * 8]);
            }
#pragma unroll
            for (int n = 0; n < 4; ++n) {
                int rB = wn * 64 + n * 16 + (lane & 15);
                bfr[n] = *reinterpret_cast<bf16x8*>(
                    &Bs[rB * 64 + (c8r ^ (rB & 7)) * 8]);
            }
#pragma unroll
            for (int m = 0; m < 4; ++m)
#pragma unroll
                for (int n = 0; n < 4; ++n)
                    acc[m][n] = __builtin_amdgcn_mfma_f32_16x16x32_bf16(
                        af[m], bfr[n], acc[m][n], 0, 0, 0);
        }
        __syncthreads();
    }
    float b1v[4];
#pragma unroll
    for (int n = 0; n < 4; ++n)
        b1v[n] = b1[bn + wn * 64 + n * 16 + (lane & 15)];
#pragma unroll
    for (int m = 0; m < 4; ++m) {
#pragma unroll
        for (int q = 0; q < 4; ++q) {
            int row = bm + wm * 64 + m * 16 + (lane >> 4) * 4 + q;
#pragma unroll
            for (int n = 0; n < 4; ++n) {
                int col = bn + wn * 64 + n * 16 + (lane & 15);
                hb[(size_t)row * 512 + col] = f2bf(tanhf(acc[m][n][q] + b1v[n]));
            }
        }
    }
}

// ---------------------------------------------------------------------------
// K2: [mu|lv] = h_bf @ Wt^T via MFMA (M=32768, N=64, K=512); epilogue fuses
// x = mu + exp(0.5 lv)*eps and xent. Wave w owns rows w*32..w*32+31.
// ---------------------------------------------------------------------------
__global__ __launch_bounds__(256) void k_mulv_mfma(
    const unsigned short* __restrict__ hbf,  // [32768][512]
    const unsigned short* __restrict__ Wt,   // [64][512]
    const float* __restrict__ bmu, const float* __restrict__ blv,
    const float* __restrict__ eps,
    float* __restrict__ x, float* __restrict__ xent)
{
    __shared__ unsigned short As[128 * 64];
    __shared__ unsigned short Bs[64 * 64];
    const int tid = threadIdx.x;
    const int bm = blockIdx.x * 128;
    const int wid = tid >> 6, lane = tid & 63;
    f32x4 acc[2][4];
#pragma unroll
    for (int m = 0; m < 2; ++m)
#pragma unroll
        for (int n = 0; n < 4; ++n)
            acc[m][n] = (f32x4){0.f, 0.f, 0.f, 0.f};

    for (int k0 = 0; k0 < 512; k0 += 64) {
#pragma unroll
        for (int r = 0; r < 4; ++r) {
            int l = tid + r * 256, row = l >> 3, c8 = l & 7;
            int sidx = row * 8 + (c8 ^ (row & 7));
            uint4 v = *reinterpret_cast<const uint4*>(
                &hbf[(size_t)(bm + row) * 512 + k0 + c8 * 8]);
            *reinterpret_cast<uint4*>(&As[sidx * 8]) = v;
        }
#pragma unroll
        for (int r = 0; r < 2; ++r) {
            int l = tid + r * 256, row = l >> 3, c8 = l & 7;
            int sidx = row * 8 + (c8 ^ (row & 7));
            uint4 v = *reinterpret_cast<const uint4*>(
                &Wt[(size_t)row * 512 + k0 + c8 * 8]);
            *reinterpret_cast<uint4*>(&Bs[sidx * 8]) = v;
        }
        __syncthreads();
#pragma unroll
        for (int kh = 0; kh < 2; ++kh) {
            const int c8r = kh * 4 + (lane >> 4);
            bf16x8 af[2], bfr[4];
#pragma unroll
            for (int m = 0; m < 2; ++m) {
                int rA = wid * 32 + m * 16 + (lane & 15);
                af[m] = *reinterpret_cast<bf16x8*>(
                    &As[rA * 64 + (c8r ^ (rA & 7)) * 8]);
            }
#pragma unroll
            for (int n = 0; n < 4; ++n) {
                int rB = n * 16 + (lane & 15);
                bfr[n] = *reinterpret_cast<bf16x8*>(
                    &Bs[rB * 64 + (c8r ^ (rB & 7)) * 8]);
            }
#pragma unroll
            for (int m = 0; m < 2; ++m)
#pragma unroll
                for (int n = 0; n < 4; ++n)
                    acc[m][n] = __builtin_amdgcn_mfma_f32_16x16x32_bf16(
                        af[m], bfr[n], acc[m][n], 0, 0, 0);
        }
        __syncthreads();
    }
    const int o0 = lane & 15, o1 = 16 + (lane & 15);
    const float bm0 = bmu[o0], bm1 = bmu[o1];
    const float bl0 = blv[o0], bl1 = blv[o1];
#pragma unroll
    for (int m = 0; m < 2; ++m) {
#pragma unroll
        for (int q = 0; q < 4; ++q) {
            int row = bm + wid * 32 + m * 16 + (lane >> 4) * 4 + q;
            float mu0 = acc[m][0][q] + bm0;
            float mu1 = acc[m][1][q] + bm1;
            float lv0 = acc[m][2][q] + bl0;
            float lv1 = acc[m][3][q] + bl1;
            float e0 = eps[(size_t)row * 32 + o0];
            float e1 = eps[(size_t)row * 32 + o1];
            x[(size_t)row * 32 + o0] = mu0 + expf(0.5f * lv0) * e0;
            x[(size_t)row * 32 + o1] = mu1 + expf(0.5f * lv1) * e1;
            float pe = (e0 * e0 + lv0) + (e1 * e1 + lv1);
            pe += __shfl_xor(pe, 1, 64);
            pe += __shfl_xor(pe, 2, 64);
            pe += __shfl_xor(pe, 4, 64);
            pe += __shfl_xor(pe, 8, 64);
            if ((lane & 15) == 0)
                xent[row] = 0.5f * (pe + 32.f * LOG2PI);
        }
    }
}

// ---------------------------------------------------------------------------
// K3: softmax_j(x[b,t-1] @ Wz + bz) written in TWO xor-permuted layouts:
// ap1[t][s][e] = a[s][s^e] (fwd), ap2[t][s][e] = a[s^e][s] (bwd).
// ---------------------------------------------------------------------------
__global__ __launch_bounds__(256) void k_loga(
    const float* __restrict__ x, const float* __restrict__ Wz,
    const float* __restrict__ bz, float* __restrict__ ap1,
    float* __restrict__ ap2)
{
    const int tid = threadIdx.x;
    const int item = blockIdx.x * 4 + (tid >> 6);  // b*NT + t
    const int lane = tid & 63;
    const int t = item & (NT - 1);
    if (t == 0) return;  // never consumed
    const int j = lane >> 3, k = lane & 7;
    const float* xr = &x[((size_t)item - 1) * 32];
    float acc = bz[lane];
#pragma unroll
    for (int e = 0; e < 32; ++e) acc = fmaf(xr[e], Wz[e * 64 + lane], acc);
    float lse = lse8_high(acc);  // LSE over j
    float p = expf(acc - lse);
    ap1[(size_t)item * 64 + j * 8 + (j ^ k)] = p;
    ap2[(size_t)item * 64 + k * 8 + (j ^ k)] = p;
}

// ---------------------------------------------------------------------------
// K4: means + log_b
// ---------------------------------------------------------------------------
__global__ __launch_bounds__(256) void k_means(
    const float* __restrict__ x, const float* __restrict__ us,
    const float* __restrict__ A, const float* __restrict__ Bu,
    const float* __restrict__ bx, const float* __restrict__ x_logvar,
    float* __restrict__ means, float* __restrict__ log_b)
{
    __shared__ float xs[32];
    __shared__ float uu[2];
    const int item = blockIdx.x;  // b*1023 + tm
    const int b = item / 1023;
    const int tm = item - b * 1023;
    const int tid = threadIdx.x;
    const int k = tid >> 5, xo = tid & 31;
    if (tid < 32) xs[tid] = x[((size_t)b * NT + tm) * 32 + tid];
    if (tid < 2) uu[tid] = us[((size_t)b * NT + tm + 1) * 2 + tid];
    __syncthreads();
    float acc = bx[k * 32 + xo];
#pragma unroll
    for (int e = 0; e < 32; ++e)
        acc = fmaf(xs[e], A[((size_t)k * 32 + e) * 32 + xo], acc);
    acc = fmaf(uu[0], Bu[((size_t)k * 2 + 0) * 32 + xo], acc);
    acc = fmaf(uu[1], Bu[((size_t)k * 2 + 1) * 32 + xo], acc);
    means[((size_t)item * 8 + k) * 32 + xo] = acc;
    float xv = x[((size_t)b * NT + tm + 1) * 32 + xo];
    float lvv = x_logvar[k * 32 + xo];
    float dd = xv - acc;
    float term = -0.5f * (dd * dd * expf(-lvv) + lvv + LOG2PI);
    for (int m = 16; m; m >>= 1) term += __shfl_down(term, m, 32);
    if (xo == 0) log_b[((size_t)b * NT + tm + 1) * 8 + k] = term;
}

__global__ __launch_bounds__(256) void k_logb0(
    const float* __restrict__ x, const float* __restrict__ x0_mean,
    const float* __restrict__ x0_logvar, float* __restrict__ log_b)
{
    const int b = blockIdx.x;
    const int tid = threadIdx.x;
    const int k = tid >> 5, xo = tid & 31;
    float xv = x[((size_t)b * NT) * 32 + xo];
    float mm = x0_mean[k * 32 + xo];
    float lvv = x0_logvar[k * 32 + xo];
    float dd = xv - mm;
    float term = -0.5f * (dd * dd * expf(-lvv) + lvv + LOG2PI);
    for (int m = 16; m; m >>= 1) term += __shfl_down(term, m, 32);
    if (xo == 0) log_b[(size_t)b * NT * 8 + k] = term;
}

// ---------------------------------------------------------------------------
// K5: forward-backward, scaled linear space, xor-factorized matvec.
// Lane holds state st = lane&7 (replicated 8x). Partners via ds_swizzle xor.
// ---------------------------------------------------------------------------
__global__ __launch_bounds__(128) void k_fb(
    const float* __restrict__ ap1, const float* __restrict__ ap2,
    const float* __restrict__ log_b, const float* __restrict__ log_init_z,
    float* __restrict__ gamma, float* __restrict__ log_px)
{
    __shared__ float fwdS[NT][8];
    __shared__ float bwdS[NT][8];
    const int b = blockIdx.x;
    const int tid = threadIdx.x;
    const int wave = tid >> 6;
    const int lane = tid & 63;
    const int st = lane & 7;
    const float* lb = &log_b[(size_t)b * NT * 8];

    float4 A0[8], A1[8];
    float beX[8], mbR[8];

    if (wave == 0) {
        const float* ap = &ap1[(size_t)b * NT * 64];
        float mz = -1e30f, mb0 = -1e30f, sz = 0.f;
        {
            float liv[8], lbv[8];
#pragma unroll
            for (int q = 0; q < 8; ++q) { liv[q] = log_init_z[q]; lbv[q] = lb[q]; }
#pragma unroll
            for (int q = 0; q < 8; ++q) {
                mz = fmaxf(mz, liv[q]);
                mb0 = fmaxf(mb0, lbv[q]);
            }
#pragma unroll
            for (int q = 0; q < 8; ++q) sz += expf(liv[q] - mz);
        }
        float alpha = (expf(log_init_z[st] - mz) / sz) * expf(lb[st] - mb0);
        float mbsum = mb0, logS = 0.f;
        if (lane < 8) fwdS[0][lane] = alpha;
#pragma unroll
        for (int r = 0; r < 8; ++r) {
            int tc = 1 + r;
            A0[r] = *reinterpret_cast<const float4*>(&ap[(size_t)tc * 64 + st * 8]);
            A1[r] = *reinterpret_cast<const float4*>(&ap[(size_t)tc * 64 + st * 8 + 4]);
            float4 l0 = *reinterpret_cast<const float4*>(&lb[(size_t)tc * 8]);
            float4 l1 = *reinterpret_cast<const float4*>(&lb[(size_t)tc * 8 + 4]);
            float mm = fmaxf(fmaxf(fmaxf(l0.x, l0.y), fmaxf(l0.z, l0.w)),
                             fmaxf(fmaxf(l1.x, l1.y), fmaxf(l1.z, l1.w)));
            beX[r] = expf(lb[(size_t)tc * 8 + st] - mm);
            mbR[r] = mm;
        }
        for (int tb = 1; tb <= 1009; tb += 8) {
#pragma unroll
            for (int r = 0; r < 8; ++r) {
                const int t = tb + r;
                float4 a0 = A0[r], a1 = A1[r];
                float bexp = beX[r];
                mbsum += mbR[r];
                {
                    int tc = t + 8;
                    if (tc > NT - 1) tc = NT - 1;
                    A0[r] = *reinterpret_cast<const float4*>(&ap[(size_t)tc * 64 + st * 8]);
                    A1[r] = *reinterpret_cast<const float4*>(&ap[(size_t)tc * 64 + st * 8 + 4]);
                    float4 l0 = *reinterpret_cast<const float4*>(&lb[(size_t)tc * 8]);
                    float4 l1 = *reinterpret_cast<const float4*>(&lb[(size_t)tc * 8 + 4]);
                    float mm = fmaxf(fmaxf(fmaxf(l0.x, l0.y), fmaxf(l0.z, l0.w)),
                                     fmaxf(fmaxf(l1.x, l1.y), fmaxf(l1.z, l1.w)));
                    beX[r] = expf(lb[(size_t)tc * 8 + st] - mm);
                    mbR[r] = mm;
                }
                float p1 = swzx<1>(alpha), p2 = swzx<2>(alpha), p3 = swzx<3>(alpha);
                float p4 = swzx<4>(alpha), p5 = swzx<5>(alpha), p6 = swzx<6>(alpha);
                float p7 = swzx<7>(alpha);
                float c0 = fmaf(a0.y, p1, a0.x * alpha);
                float c1 = fmaf(a0.w, p3, a0.z * p2);
                float c2 = fmaf(a1.y, p5, a1.x * p4);
                float c3 = fmaf(a1.w, p7, a1.z * p6);
                alpha = ((c0 + c1) + (c2 + c3)) * bexp;
                if (lane < 8) fwdS[t][lane] = alpha;
                if (r == 2 || r == 6) {
                    float s1 = alpha + swzx<1>(alpha);
                    float s2 = s1 + swzx<2>(s1);
                    float s4 = s2 + swzx<4>(s2);
                    logS += logf(s4);
                    alpha *= __builtin_amdgcn_rcpf(s4);
                }
            }
        }
#pragma unroll
        for (int r = 0; r < 7; ++r) {
            const int t = 1017 + r;
            float4 a0 = A0[r], a1 = A1[r];
            float bexp = beX[r];
            mbsum += mbR[r];
            float p1 = swzx<1>(alpha), p2 = swzx<2>(alpha), p3 = swzx<3>(alpha);
            float p4 = swzx<4>(alpha), p5 = swzx<5>(alpha), p6 = swzx<6>(alpha);
            float p7 = swzx<7>(alpha);
            float c0 = fmaf(a0.y, p1, a0.x * alpha);
            float c1 = fmaf(a0.w, p3, a0.z * p2);
            float c2 = fmaf(a1.y, p5, a1.x * p4);
            float c3 = fmaf(a1.w, p7, a1.z * p6);
            alpha = ((c0 + c1) + (c2 + c3)) * bexp;
            if (lane < 8) fwdS[t][lane] = alpha;
            if (r == 2 || r == 6) {
                float s1 = alpha + swzx<1>(alpha);
                float s2 = s1 + swzx<2>(s1);
                float s4 = s2 + swzx<4>(s2);
                logS += logf(s4);
                alpha *= __builtin_amdgcn_rcpf(s4);
            }
        }
        float s1 = alpha + swzx<1>(alpha);
        float s2 = s1 + swzx<2>(s1);
        float s4 = s2 + swzx<4>(s2);
        if (lane == 0) log_px[b] = mbsum + logS + logf(s4);
    } else {
        const float* ap = &ap2[(size_t)b * NT * 64];
        float beta = 1.f;
        if (lane < 8) bwdS[NT - 1][lane] = 1.f;
#pragma unroll
        for (int r = 0; r < 8; ++r) {
            int tc = 1023 - r;
            A0[r] = *reinterpret_cast<const float4*>(&ap[(size_t)tc * 64 + st * 8]);
            A1[r] = *reinterpret_cast<const float4*>(&ap[(size_t)tc * 64 + st * 8 + 4]);
            float4 l0 = *reinterpret_cast<const float4*>(&lb[(size_t)tc * 8]);
            float4 l1 = *reinterpret_cast<const float4*>(&lb[(size_t)tc * 8 + 4]);
            float mm = fmaxf(fmaxf(fmaxf(l0.x, l0.y), fmaxf(l0.z, l0.w)),
                             fmaxf(fmaxf(l1.x, l1.y), fmaxf(l1.z, l1.w)));
            beX[r] = expf(lb[(size_t)tc * 8 + st] - mm);
        }
        for (int tb = 1023; tb >= 15; tb -= 8) {
#pragma unroll
            for (int r = 0; r < 8; ++r) {
                const int t = tb - r;
                float4 a0 = A0[r], a1 = A1[r];
                float w = beta * beX[r];
                {
                    int tc = t - 8;
                    if (tc < 1) tc = 1;
                    A0[r] = *reinterpret_cast<const float4*>(&ap[(size_t)tc * 64 + st * 8]);
                    A1[r] = *reinterpret_cast<const float4*>(&ap[(size_t)tc * 64 + st * 8 + 4]);
                    float4 l0 = *reinterpret_cast<const float4*>(&lb[(size_t)tc * 8]);
                    float4 l1 = *reinterpret_cast<const float4*>(&lb[(size_t)tc * 8 + 4]);
                    float mm = fmaxf(fmaxf(fmaxf(l0.x, l0.y), fmaxf(l0.z, l0.w)),
                                     fmaxf(fmaxf(l1.x, l1.y), fmaxf(l1.z, l1.w)));
                    beX[r] = expf(lb[(size_t)tc * 8 + st] - mm);
                }
                float p1 = swzx<1>(w), p2 = swzx<2>(w), p3 = swzx<3>(w);
                float p4 = swzx<4>(w), p5 = swzx<5>(w), p6 = swzx<6>(w);
                float p7 = swzx<7>(w);
                float c0 = fmaf(a0.y, p1, a0.x * w);
                float c1 = fmaf(a0.w, p3, a0.z * p2);
                float c2 = fmaf(a1.y, p5, a1.x * p4);
                float c3 = fmaf(a1.w, p7, a1.z * p6);
                beta = (c0 + c1) + (c2 + c3);
                if (lane < 8) bwdS[t - 1][lane] = beta;
                if (r == 3 || r == 7) {
                    float s1 = beta + swzx<1>(beta);
                    float s2 = s1 + swzx<2>(s1);
                    float s4 = s2 + swzx<4>(s2);
                    beta *= __builtin_amdgcn_rcpf(s4);
                }
            }
        }
#pragma unroll
        for (int r = 0; r < 7; ++r) {
            const int t = 7 - r;
            float4 a0 = A0[r], a1 = A1[r];
            float w = beta * beX[r];
            float p1 = swzx<1>(w), p2 = swzx<2>(w), p3 = swzx<3>(w);
            float p4 = swzx<4>(w), p5 = swzx<5>(w), p6 = swzx<6>(w);
            float p7 = swzx<7>(w);
            float c0 = fmaf(a0.y, p1, a0.x * w);
            float c1 = fmaf(a0.w, p3, a0.z * p2);
            float c2 = fmaf(a1.y, p5, a1.x * p4);
            float c3 = fmaf(a1.w, p7, a1.z * p6);
            beta = (c0 + c1) + (c2 + c3);
            if (lane < 8) bwdS[t - 1][lane] = beta;
            if (r == 3) {
                float s1 = beta + swzx<1>(beta);
                float s2 = s1 + swzx<2>(s1);
                float s4 = s2 + swzx<4>(s2);
                beta *= __builtin_amdgcn_rcpf(s4);
            }
        }
    }
    __syncthreads();
    for (int t = tid; t < NT; t += 128) {
        float lg[8], ssum = 0.f;
#pragma unroll
        for (int q = 0; q < 8; ++q) {
            lg[q] = fwdS[t][q] * bwdS[t][q];
            ssum += lg[q];
        }
        float inv = __builtin_amdgcn_rcpf(ssum);
#pragma unroll
        for (int q = 0; q < 8; ++q)
            gamma[((size_t)b * NT + t) * 8 + q] = lg[q] * inv;
    }
}

// ---------------------------------------------------------------------------
// K6: emission + reduction
// ---------------------------------------------------------------------------
__global__ __launch_bounds__(256) void k_emit(
    const float* __restrict__ ys, const float* __restrict__ x,
    const float* __restrict__ means, const float* __restrict__ gamma,
    const float* __restrict__ C, const float* __restrict__ dvec,
    const float* __restrict__ y_logvar, const float* __restrict__ xent,
    float* __restrict__ red)
{
    __shared__ float xg[8][32];
    __shared__ float gs[8][8];
    __shared__ float wsum[8][4];
    const int tid = threadIdx.x;
    const int itemBase = blockIdx.x * 8;
    const int b = itemBase >> 10;
    const int t0 = itemBase & (NT - 1);
    if (tid < 64) {
        int it = tid >> 3, q = tid & 7;
        if (t0 + it > 0)
            gs[it][q] = gamma[((size_t)itemBase + it) * 8 + q];
    }
    __syncthreads();
    {
        int it = tid >> 5, xo = tid & 31;
        int t = t0 + it;
        float v;
        if (t == 0) {
            v = x[((size_t)itemBase + it) * 32 + xo];
        } else {
            const float* mp = &means[(((size_t)b * 1023 + (t - 1)) * 8) * 32 + xo];
            v = 0.f;
#pragma unroll
            for (int q = 0; q < 8; ++q) v = fmaf(mp[q * 32], gs[it][q], v);
        }
        xg[it][xo] = v;
    }
    __syncthreads();
    float acc[8][2] = {};
    for (int e = 0; e < 32; ++e) {
        float c0 = C[e * 512 + tid];
        float c1 = C[e * 512 + tid + 256];
#pragma unroll
        for (int it = 0; it < 8; ++it) {
            float xv = xg[it][e];
            acc[it][0] = fmaf(xv, c0, acc[it][0]);
            acc[it][1] = fmaf(xv, c1, acc[it][1]);
        }
    }
    float d0 = dvec[tid], d1 = dvec[tid + 256];
    float ylv0 = y_logvar[tid], ylv1 = y_logvar[tid + 256];
    float iv0 = expf(-ylv0), iv1 = expf(-ylv1);
    float base0 = ylv0 + LOG2PI, base1 = ylv1 + LOG2PI;
#pragma unroll
    for (int it = 0; it < 8; ++it) {
        const float* yrow = &ys[((size_t)itemBase + it) * 512];
        float df0 = yrow[tid] - (acc[it][0] + d0);
        float df1 = yrow[tid + 256] - (acc[it][1] + d1);
        float lsum = -0.5f * (df0 * df0 * iv0 + base0)
                   - 0.5f * (df1 * df1 * iv1 + base1);
#pragma unroll
        for (int m = 1; m < 64; m <<= 1) lsum += __shfl_xor(lsum, m, 64);
        if ((tid & 63) == 0) wsum[it][tid >> 6] = lsum;
    }
    __syncthreads();
    if (tid < 8)
        red[itemBase + tid] = wsum[tid][0] + wsum[tid][1] + wsum[tid][2]
                            + wsum[tid][3] + xent[itemBase + tid];
}

__global__ __launch_bounds__(256) void k_final(
    const float* __restrict__ red, const float* __restrict__ log_px,
    float* __restrict__ out)
{
    __shared__ float ssum[4];
    float s = 0.f;
    for (int i = threadIdx.x; i < NB * NT; i += 256) s += red[i];
    if (threadIdx.x < NB) s += log_px[threadIdx.x];
#pragma unroll
    for (int m = 1; m < 64; m <<= 1) s += __shfl_xor(s, m, 64);
    if ((threadIdx.x & 63) == 0) ssum[threadIdx.x >> 6] = s;
    __syncthreads();
    if (threadIdx.x == 0)
        out[0] = (ssum[0] + ssum[1] + ssum[2] + ssum[3]) / (float)NB;
}

// ---------------------------------------------------------------------------
extern "C" void kernel_launch(void* const* d_in, const int* in_sizes, int n_in,
                              void* d_out, int out_size, void* d_ws,
                              size_t ws_size, hipStream_t stream)
{
    const float* ys        = (const float*)d_in[0];
    const float* us        = (const float*)d_in[1];
    const float* eps       = (const float*)d_in[2];
    const float* W1        = (const float*)d_in[3];
    const float* b1        = (const float*)d_in[4];
    const float* Wmu       = (const float*)d_in[5];
    const float* bmu       = (const float*)d_in[6];
    const float* Wlv       = (const float*)d_in[7];
    const float* blv       = (const float*)d_in[8];
    const float* Wz        = (const float*)d_in[9];
    const float* bz        = (const float*)d_in[10];
    const float* A         = (const float*)d_in[11];
    const float* Bu        = (const float*)d_in[12];
    const float* bx        = (const float*)d_in[13];
    const float* x_logvar  = (const float*)d_in[14];
    const float* x0_mean   = (const float*)d_in[15];
    const float* x0_logvar = (const float*)d_in[16];
    const float* C         = (const float*)d_in[17];
    const float* dv        = (const float*)d_in[18];
    const float* y_logvar  = (const float*)d_in[19];
    const float* log_init_z= (const float*)d_in[20];
    float* out = (float*)d_out;

    float* ws = (float*)d_ws;
    float* hbf_f  = ws;                    //  8,388,608 (h bf16)
    float* x      = hbf_f + 8388608;       //  1,048,576
    float* xent   = x + 1048576;           //     32,768
    float* ap1    = xent + 32768;          //  2,097,152
    float* ap2    = ap1 + 2097152;         //  2,097,152
    float* log_b  = ap2 + 2097152;         //    262,144
    float* means  = log_b + 262144;        //  8,380,416
    float* gam    = means + 8380416;       //    262,144
    float* log_px = gam + 262144;          //         32
    float* red    = log_px + 32;           //     32,768
    float* w1t_f  = red + 32768;           //    131,072 (W1^T bf16)
    float* wmlv_f = w1t_f + 131072;        //     16,384 (Wmu|Wlv^T bf16)

    unsigned short* hbf  = (unsigned short*)hbf_f;
    unsigned short* w1t  = (unsigned short*)w1t_f;
    unsigned short* wmlv = (unsigned short*)wmlv_f;

    k_castT    <<<dim3(16, 16), 256, 0, stream>>>(W1, w1t);
    k_cast_mulv<<<dim3(16, 2), 256, 0, stream>>>(Wmu, Wlv, wmlv);
    k_gemm_h_mfma<<<dim3(4, 256), 256, 0, stream>>>(ys, w1t, b1, hbf);
    k_mulv_mfma<<<256, 256, 0, stream>>>(hbf, wmlv, bmu, blv, eps, x, xent);
    k_loga <<<8192, 256, 0, stream>>>(x, Wz, bz, ap1, ap2);
    k_means<<<32 * 1023, 256, 0, stream>>>(x, us, A, Bu, bx, x_logvar, means, log_b);
    k_logb0<<<32, 256, 0, stream>>>(x, x0_mean, x0_logvar, log_b);
    k_fb   <<<32, 128, 0, stream>>>(ap1, ap2, log_b, log_init_z, gam, log_px);
    k_emit <<<4096, 256, 0, stream>>>(ys, x, means, gam, C, dv, y_logvar, xent, red);
    k_final<<<1, 256, 0, stream>>>(red, log_px, out);
}

// Round 4
// 379.164 us; speedup vs baseline: 3.4213x; 1.2846x over previous
//
#include <hip/hip_runtime.h>
#include <math.h>

#define LOG2PI 1.8378770664093453f

// Problem sizes (fixed)
#define NB 32
#define NT 1024
#define ND 512
#define NH 512
#define NX 32
#define NK 8
#define NU 2

typedef __attribute__((ext_vector_type(8))) short bf16x8;
typedef __attribute__((ext_vector_type(4))) float f32x4;

__device__ __forceinline__ unsigned short f2bf(float f) {
    unsigned u = __float_as_uint(f);
    unsigned r = (u + 0x7FFF + ((u >> 16) & 1)) >> 16;
    return (unsigned short)r;
}

// ---------------------------------------------------------------------------
// DPP xor-shuffles within 8-lane groups (VALU pipe, no LDS latency)
// quad_perm codes: xor1=[1,0,3,2]=0xB1, xor2=[2,3,0,1]=0x4E, xor3=[3,2,1,0]=0x1B
// row_half_mirror (xor7 within 8) = 0x141
// ---------------------------------------------------------------------------
#define DPP_X1 0xB1
#define DPP_X2 0x4E
#define DPP_X3 0x1B
#define DPP_X7 0x141

template <int CTRL>
__device__ __forceinline__ float dppx(float v) {
    return __int_as_float(__builtin_amdgcn_update_dpp(
        0, __float_as_int(v), CTRL, 0xF, 0xF, true));
}

// alpha' = A * alpha (xor-factorized; row in a0|a1, alpha replicated per 8)
__device__ __forceinline__ float fb_matvec(float4 a0, float4 a1, float v) {
    float p1 = dppx<DPP_X1>(v);
    float p2 = dppx<DPP_X2>(v);
    float p3 = dppx<DPP_X3>(v);
    float p7 = dppx<DPP_X7>(v);
    float p4 = dppx<DPP_X7>(p3);
    float p5 = dppx<DPP_X7>(p2);
    float p6 = dppx<DPP_X7>(p1);
    float c0 = fmaf(a0.y, p1, a0.x * v);
    float c1 = fmaf(a0.w, p3, a0.z * p2);
    float c2 = fmaf(a1.y, p5, a1.x * p4);
    float c3 = fmaf(a1.w, p7, a1.z * p6);
    return (c0 + c1) + (c2 + c3);
}

// beta' = A^T * w using the SAME ap1 rows: beta'_k = sum_e dppxor_e(row[e]*w)
__device__ __forceinline__ float fb_matvecT(float4 a0, float4 a1, float w) {
    float q0 = a0.x * w;
    float t1 = dppx<DPP_X1>(a0.y * w);
    float t2 = dppx<DPP_X2>(a0.z * w);
    float t3 = dppx<DPP_X3>(a0.w * w);
    float t7 = dppx<DPP_X7>(a1.w * w);
    float t4 = dppx<DPP_X7>(dppx<DPP_X3>(a1.x * w));
    float t5 = dppx<DPP_X7>(dppx<DPP_X2>(a1.y * w));
    float t6 = dppx<DPP_X7>(dppx<DPP_X1>(a1.z * w));
    return ((q0 + t1) + (t2 + t3)) + ((t4 + t5) + (t6 + t7));
}

// sum over the 8-lane group (replicated result)
__device__ __forceinline__ float gsum8(float v) {
    float s = v + dppx<DPP_X1>(v);
    s = s + dppx<DPP_X2>(s);
    s = s + dppx<DPP_X7>(dppx<DPP_X3>(s));  // + xor4 of s
    return s;
}

__device__ __forceinline__ float lse8_high(float v) {
    float m = v;
    m = fmaxf(m, __shfl_xor(m, 8, 64));
    m = fmaxf(m, __shfl_xor(m, 16, 64));
    m = fmaxf(m, __shfl_xor(m, 32, 64));
    float s = expf(v - m);
    s += __shfl_xor(s, 8, 64);
    s += __shfl_xor(s, 16, 64);
    s += __shfl_xor(s, 32, 64);
    return m + logf(s);
}

// ---------------------------------------------------------------------------
// W1 [K=512][N=512] f32 -> W1T [N][K] bf16
// ---------------------------------------------------------------------------
__global__ __launch_bounds__(256) void k_castT(
    const float* __restrict__ W, unsigned short* __restrict__ WT)
{
    __shared__ float tile[32][33];
    const int bx = blockIdx.x * 32;  // k-base
    const int by = blockIdx.y * 32;  // n-base
    const int tx = threadIdx.x & 31, ty = threadIdx.x >> 5;
    for (int i = ty; i < 32; i += 8)
        tile[i][tx] = W[(size_t)(bx + i) * 512 + by + tx];
    __syncthreads();
    for (int i = ty; i < 32; i += 8)
        WT[(size_t)(by + i) * 512 + bx + tx] = f2bf(tile[tx][i]);
}

// Wmu/Wlv [512][32] f32 -> out [64][512] bf16 (rows 0-31 mu^T, 32-63 lv^T)
__global__ __launch_bounds__(256) void k_cast_mulv(
    const float* __restrict__ Wmu, const float* __restrict__ Wlv,
    unsigned short* __restrict__ out)
{
    __shared__ float tile[32][33];
    const float* W = blockIdx.y ? Wlv : Wmu;
    const int base = blockIdx.y * 32;
    const int g = blockIdx.x;  // k-chunk
    const int tx = threadIdx.x & 31, ty = threadIdx.x >> 5;
    for (int i = ty; i < 32; i += 8)
        tile[i][tx] = W[(size_t)(g * 32 + i) * 32 + tx];  // [kk][o]
    __syncthreads();
    for (int i = ty; i < 32; i += 8)
        out[(size_t)(base + i) * 512 + g * 32 + tx] = f2bf(tile[tx][i]);
}

// ---------------------------------------------------------------------------
// K1: h_bf = bf16(tanh(ys @ W1 + b1)). Reads f32 ys, casts in-register.
// ---------------------------------------------------------------------------
__global__ __launch_bounds__(256) void k_gemm_h_mfma(
    const float* __restrict__ ys,            // [32768][512] f32
    const unsigned short* __restrict__ Bbf,  // [512][512] bf16 (=W1^T)
    const float* __restrict__ b1, unsigned short* __restrict__ hb)
{
    __shared__ unsigned short As[128 * 64];
    __shared__ unsigned short Bs[128 * 64];
    const int tid = threadIdx.x;
    const int bm = blockIdx.y * 128;
    const int bn = blockIdx.x * 128;
    const int wid = tid >> 6, lane = tid & 63;
    const int wm = wid >> 1, wn = wid & 1;

    f32x4 acc[4][4];
#pragma unroll
    for (int m = 0; m < 4; ++m)
#pragma unroll
        for (int n = 0; n < 4; ++n)
            acc[m][n] = (f32x4){0.f, 0.f, 0.f, 0.f};

    for (int k0 = 0; k0 < 512; k0 += 64) {
#pragma unroll
        for (int r = 0; r < 4; ++r) {
            int l = tid + r * 256;
            int row = l >> 3, c8 = l & 7;
            int sidx = row * 8 + (c8 ^ (row & 7));
            const float4 f0 = *reinterpret_cast<const float4*>(
                &ys[(size_t)(bm + row) * 512 + k0 + c8 * 8]);
            const float4 f1 = *reinterpret_cast<const float4*>(
                &ys[(size_t)(bm + row) * 512 + k0 + c8 * 8 + 4]);
            uint4 ua;
            ua.x = (unsigned)f2bf(f0.x) | ((unsigned)f2bf(f0.y) << 16);
            ua.y = (unsigned)f2bf(f0.z) | ((unsigned)f2bf(f0.w) << 16);
            ua.z = (unsigned)f2bf(f1.x) | ((unsigned)f2bf(f1.y) << 16);
            ua.w = (unsigned)f2bf(f1.z) | ((unsigned)f2bf(f1.w) << 16);
            *reinterpret_cast<uint4*>(&As[sidx * 8]) = ua;
            uint4 vb = *reinterpret_cast<const uint4*>(
                &Bbf[(size_t)(bn + row) * 512 + k0 + c8 * 8]);
            *reinterpret_cast<uint4*>(&Bs[sidx * 8]) = vb;
        }
        __syncthreads();
#pragma unroll
        for (int kh = 0; kh < 2; ++kh) {
            bf16x8 af[4], bfr[4];
            const int c8r = kh * 4 + (lane >> 4);
#pragma unroll
            for (int m = 0; m < 4; ++m) {
                int rA = wm * 64 + m * 16 + (lane & 15);
                af[m] = *reinterpret_cast<bf16x8*>(
                    &As[rA * 64 + (c8r ^ (rA & 7)) * 8]);
            }
#pragma unroll
            for (int n = 0; n < 4; ++n) {
                int rB = wn * 64 + n * 16 + (lane & 15);
                bfr[n] = *reinterpret_cast<bf16x8*>(
                    &Bs[rB * 64 + (c8r ^ (rB & 7)) * 8]);
            }
#pragma unroll
            for (int m = 0; m < 4; ++m)
#pragma unroll
                for (int n = 0; n < 4; ++n)
                    acc[m][n] = __builtin_amdgcn_mfma_f32_16x16x32_bf16(
                        af[m], bfr[n], acc[m][n], 0, 0, 0);
        }
        __syncthreads();
    }
    float b1v[4];
#pragma unroll
    for (int n = 0; n < 4; ++n)
        b1v[n] = b1[bn + wn * 64 + n * 16 + (lane & 15)];
#pragma unroll
    for (int m = 0; m < 4; ++m) {
#pragma unroll
        for (int q = 0; q < 4; ++q) {
            int row = bm + wm * 64 + m * 16 + (lane >> 4) * 4 + q;
#pragma unroll
            for (int n = 0; n < 4; ++n) {
                int col = bn + wn * 64 + n * 16 + (lane & 15);
                hb[(size_t)row * 512 + col] = f2bf(tanhf(acc[m][n][q] + b1v[n]));
            }
        }
    }
}

// ---------------------------------------------------------------------------
// K2: [mu|lv] = h_bf @ Wt^T via MFMA; epilogue fuses x = mu+exp(.5lv)*eps, xent
// ---------------------------------------------------------------------------
__global__ __launch_bounds__(256) void k_mulv_mfma(
    const unsigned short* __restrict__ hbf,  // [32768][512]
    const unsigned short* __restrict__ Wt,   // [64][512]
    const float* __restrict__ bmu, const float* __restrict__ blv,
    const float* __restrict__ eps,
    float* __restrict__ x, float* __restrict__ xent)
{
    __shared__ unsigned short As[128 * 64];
    __shared__ unsigned short Bs[64 * 64];
    const int tid = threadIdx.x;
    const int bm = blockIdx.x * 128;
    const int wid = tid >> 6, lane = tid & 63;
    f32x4 acc[2][4];
#pragma unroll
    for (int m = 0; m < 2; ++m)
#pragma unroll
        for (int n = 0; n < 4; ++n)
            acc[m][n] = (f32x4){0.f, 0.f, 0.f, 0.f};

    for (int k0 = 0; k0 < 512; k0 += 64) {
#pragma unroll
        for (int r = 0; r < 4; ++r) {
            int l = tid + r * 256, row = l >> 3, c8 = l & 7;
            int sidx = row * 8 + (c8 ^ (row & 7));
            uint4 v = *reinterpret_cast<const uint4*>(
                &hbf[(size_t)(bm + row) * 512 + k0 + c8 * 8]);
            *reinterpret_cast<uint4*>(&As[sidx * 8]) = v;
        }
#pragma unroll
        for (int r = 0; r < 2; ++r) {
            int l = tid + r * 256, row = l >> 3, c8 = l & 7;
            int sidx = row * 8 + (c8 ^ (row & 7));
            uint4 v = *reinterpret_cast<const uint4*>(
                &Wt[(size_t)row * 512 + k0 + c8 * 8]);
            *reinterpret_cast<uint4*>(&Bs[sidx * 8]) = v;
        }
        __syncthreads();
#pragma unroll
        for (int kh = 0; kh < 2; ++kh) {
            const int c8r = kh * 4 + (lane >> 4);
            bf16x8 af[2], bfr[4];
#pragma unroll
            for (int m = 0; m < 2; ++m) {
                int rA = wid * 32 + m * 16 + (lane & 15);
                af[m] = *reinterpret_cast<bf16x8*>(
                    &As[rA * 64 + (c8r ^ (rA & 7)) * 8]);
            }
#pragma unroll
            for (int n = 0; n < 4; ++n) {
                int rB = n * 16 + (lane & 15);
                bfr[n] = *reinterpret_cast<bf16x8*>(
                    &Bs[rB * 64 + (c8r ^ (rB & 7)) * 8]);
            }
#pragma unroll
            for (int m = 0; m < 2; ++m)
#pragma unroll
                for (int n = 0; n < 4; ++n)
                    acc[m][n] = __builtin_amdgcn_mfma_f32_16x16x32_bf16(
                        af[m], bfr[n], acc[m][n], 0, 0, 0);
        }
        __syncthreads();
    }
    const int o0 = lane & 15, o1 = 16 + (lane & 15);
    const float bm0 = bmu[o0], bm1 = bmu[o1];
    const float bl0 = blv[o0], bl1 = blv[o1];
#pragma unroll
    for (int m = 0; m < 2; ++m) {
#pragma unroll
        for (int q = 0; q < 4; ++q) {
            int row = bm + wid * 32 + m * 16 + (lane >> 4) * 4 + q;
            float mu0 = acc[m][0][q] + bm0;
            float mu1 = acc[m][1][q] + bm1;
            float lv0 = acc[m][2][q] + bl0;
            float lv1 = acc[m][3][q] + bl1;
            float e0 = eps[(size_t)row * 32 + o0];
            float e1 = eps[(size_t)row * 32 + o1];
            x[(size_t)row * 32 + o0] = mu0 + expf(0.5f * lv0) * e0;
            x[(size_t)row * 32 + o1] = mu1 + expf(0.5f * lv1) * e1;
            float pe = (e0 * e0 + lv0) + (e1 * e1 + lv1);
            pe += __shfl_xor(pe, 1, 64);
            pe += __shfl_xor(pe, 2, 64);
            pe += __shfl_xor(pe, 4, 64);
            pe += __shfl_xor(pe, 8, 64);
            if ((lane & 15) == 0)
                xent[row] = 0.5f * (pe + 32.f * LOG2PI);
        }
    }
}

// ---------------------------------------------------------------------------
// K3: softmax_j(x[b,t-1] @ Wz + bz) -> ap1[t][s][e] = a[s][s^e] only.
// ---------------------------------------------------------------------------
__global__ __launch_bounds__(256) void k_loga(
    const float* __restrict__ x, const float* __restrict__ Wz,
    const float* __restrict__ bz, float* __restrict__ ap1)
{
    const int tid = threadIdx.x;
    const int item = blockIdx.x * 4 + (tid >> 6);  // b*NT + t
    const int lane = tid & 63;
    const int t = item & (NT - 1);
    if (t == 0) return;  // never consumed
    const int j = lane >> 3, k = lane & 7;
    const float* xr = &x[((size_t)item - 1) * 32];
    float acc = bz[lane];
#pragma unroll
    for (int e = 0; e < 32; ++e) acc = fmaf(xr[e], Wz[e * 64 + lane], acc);
    float lse = lse8_high(acc);  // LSE over j
    ap1[(size_t)item * 64 + j * 8 + (j ^ k)] = expf(acc - lse);
}

// ---------------------------------------------------------------------------
// K4: means + log_b
// ---------------------------------------------------------------------------
__global__ __launch_bounds__(256) void k_means(
    const float* __restrict__ x, const float* __restrict__ us,
    const float* __restrict__ A, const float* __restrict__ Bu,
    const float* __restrict__ bx, const float* __restrict__ x_logvar,
    float* __restrict__ means, float* __restrict__ log_b)
{
    __shared__ float xs[32];
    __shared__ float uu[2];
    const int item = blockIdx.x;  // b*1023 + tm
    const int b = item / 1023;
    const int tm = item - b * 1023;
    const int tid = threadIdx.x;
    const int k = tid >> 5, xo = tid & 31;
    if (tid < 32) xs[tid] = x[((size_t)b * NT + tm) * 32 + tid];
    if (tid < 2) uu[tid] = us[((size_t)b * NT + tm + 1) * 2 + tid];
    __syncthreads();
    float acc = bx[k * 32 + xo];
#pragma unroll
    for (int e = 0; e < 32; ++e)
        acc = fmaf(xs[e], A[((size_t)k * 32 + e) * 32 + xo], acc);
    acc = fmaf(uu[0], Bu[((size_t)k * 2 + 0) * 32 + xo], acc);
    acc = fmaf(uu[1], Bu[((size_t)k * 2 + 1) * 32 + xo], acc);
    means[((size_t)item * 8 + k) * 32 + xo] = acc;
    float xv = x[((size_t)b * NT + tm + 1) * 32 + xo];
    float lvv = x_logvar[k * 32 + xo];
    float dd = xv - acc;
    float term = -0.5f * (dd * dd * expf(-lvv) + lvv + LOG2PI);
    for (int m = 16; m; m >>= 1) term += __shfl_down(term, m, 32);
    if (xo == 0) log_b[((size_t)b * NT + tm + 1) * 8 + k] = term;
}

__global__ __launch_bounds__(256) void k_logb0(
    const float* __restrict__ x, const float* __restrict__ x0_mean,
    const float* __restrict__ x0_logvar, float* __restrict__ log_b)
{
    const int b = blockIdx.x;
    const int tid = threadIdx.x;
    const int k = tid >> 5, xo = tid & 31;
    float xv = x[((size_t)b * NT) * 32 + xo];
    float mm = x0_mean[k * 32 + xo];
    float lvv = x0_logvar[k * 32 + xo];
    float dd = xv - mm;
    float term = -0.5f * (dd * dd * expf(-lvv) + lvv + LOG2PI);
    for (int m = 16; m; m >>= 1) term += __shfl_down(term, m, 32);
    if (xo == 0) log_b[(size_t)b * NT * 8 + k] = term;
}

// ---------------------------------------------------------------------------
// K4c: prep for the scan: bexp[b][t][k] = exp(lb - max_k lb),
// mbsum[b] = sum_t max_k lb. Deterministic LDS tree reduction.
// ---------------------------------------------------------------------------
__global__ __launch_bounds__(256) void k_prep(
    const float* __restrict__ log_b, float* __restrict__ bexp,
    float* __restrict__ mbsum)
{
    __shared__ float part[256];
    const int b = blockIdx.x;
    const int tid = threadIdx.x;
    float msum = 0.f;
    for (int t = tid; t < NT; t += 256) {
        const float* lbp = &log_b[((size_t)b * NT + t) * 8];
        float4 l0 = *reinterpret_cast<const float4*>(lbp);
        float4 l1 = *reinterpret_cast<const float4*>(lbp + 4);
        float mm = fmaxf(fmaxf(fmaxf(l0.x, l0.y), fmaxf(l0.z, l0.w)),
                         fmaxf(fmaxf(l1.x, l1.y), fmaxf(l1.z, l1.w)));
        float4 e0, e1;
        e0.x = expf(l0.x - mm); e0.y = expf(l0.y - mm);
        e0.z = expf(l0.z - mm); e0.w = expf(l0.w - mm);
        e1.x = expf(l1.x - mm); e1.y = expf(l1.y - mm);
        e1.z = expf(l1.z - mm); e1.w = expf(l1.w - mm);
        float* bp = &bexp[((size_t)b * NT + t) * 8];
        *reinterpret_cast<float4*>(bp) = e0;
        *reinterpret_cast<float4*>(bp + 4) = e1;
        msum += mm;
    }
    part[tid] = msum;
    __syncthreads();
    for (int s = 128; s; s >>= 1) {
        if (tid < s) part[tid] += part[tid + s];
        __syncthreads();
    }
    if (tid == 0) mbsum[b] = part[0];
}

// ---------------------------------------------------------------------------
// K5: forward-backward, scaled linear space, DPP-only cross-lane.
// Lane holds state st = lane&7 (replicated 8x).
// ---------------------------------------------------------------------------
__global__ __launch_bounds__(128) void k_fb(
    const float* __restrict__ ap1, const float* __restrict__ bexp,
    const float* __restrict__ mbsum, const float* __restrict__ log_init_z,
    float* __restrict__ gamma, float* __restrict__ log_px)
{
    __shared__ float fwdS[NT][8];
    __shared__ float bwdS[NT][8];
    const int b = blockIdx.x;
    const int tid = threadIdx.x;
    const int wave = tid >> 6;
    const int lane = tid & 63;
    const int st = lane & 7;
    const float* ap = &ap1[(size_t)b * NT * 64];
    const float* be = &bexp[(size_t)b * NT * 8];

    float4 A0[8], A1[8];
    float beR[8];

    if (wave == 0) {
        // ---- forward ----
        float mz = -1e30f, sz = 0.f;
        float liv[8];
#pragma unroll
        for (int q = 0; q < 8; ++q) liv[q] = log_init_z[q];
#pragma unroll
        for (int q = 0; q < 8; ++q) mz = fmaxf(mz, liv[q]);
#pragma unroll
        for (int q = 0; q < 8; ++q) sz += expf(liv[q] - mz);
        float alpha = (expf(liv[st] - mz) / sz) * be[st];
        float logS = 0.f;
        if (lane < 8) fwdS[0][lane] = alpha;
#pragma unroll
        for (int r = 0; r < 8; ++r) {
            int tc = 1 + r;
            A0[r] = *reinterpret_cast<const float4*>(&ap[(size_t)tc * 64 + st * 8]);
            A1[r] = *reinterpret_cast<const float4*>(&ap[(size_t)tc * 64 + st * 8 + 4]);
            beR[r] = be[(size_t)tc * 8 + st];
        }
        for (int tb = 1; tb <= 1009; tb += 8) {
#pragma unroll
            for (int r = 0; r < 8; ++r) {
                const int t = tb + r;
                float4 a0 = A0[r], a1 = A1[r];
                float bv = beR[r];
                {
                    int tc = t + 8;
                    if (tc > NT - 1) tc = NT - 1;
                    A0[r] = *reinterpret_cast<const float4*>(&ap[(size_t)tc * 64 + st * 8]);
                    A1[r] = *reinterpret_cast<const float4*>(&ap[(size_t)tc * 64 + st * 8 + 4]);
                    beR[r] = be[(size_t)tc * 8 + st];
                }
                alpha = fb_matvec(a0, a1, alpha) * bv;
                if (lane < 8) fwdS[t][lane] = alpha;
                if (r == 2 || r == 6) {
                    float s4 = gsum8(alpha);
                    logS += __logf(s4);
                    alpha *= __builtin_amdgcn_rcpf(s4);
                }
            }
        }
#pragma unroll
        for (int r = 0; r < 7; ++r) {
            const int t = 1017 + r;
            float4 a0 = A0[r], a1 = A1[r];
            float bv = beR[r];
            alpha = fb_matvec(a0, a1, alpha) * bv;
            if (lane < 8) fwdS[t][lane] = alpha;
            if (r == 2 || r == 6) {
                float s4 = gsum8(alpha);
                logS += __logf(s4);
                alpha *= __builtin_amdgcn_rcpf(s4);
            }
        }
        float s4 = gsum8(alpha);
        if (lane == 0) log_px[b] = mbsum[b] + logS + __logf(s4);
    } else {
        // ---- backward ----
        float beta = 1.f;
        if (lane < 8) bwdS[NT - 1][lane] = 1.f;
#pragma unroll
        for (int r = 0; r < 8; ++r) {
            int tc = 1023 - r;
            A0[r] = *reinterpret_cast<const float4*>(&ap[(size_t)tc * 64 + st * 8]);
            A1[r] = *reinterpret_cast<const float4*>(&ap[(size_t)tc * 64 + st * 8 + 4]);
            beR[r] = be[(size_t)tc * 8 + st];
        }
        for (int tb = 1023; tb >= 15; tb -= 8) {
#pragma unroll
            for (int r = 0; r < 8; ++r) {
                const int t = tb - r;
                float4 a0 = A0[r], a1 = A1[r];
                float w = beta * beR[r];
                {
                    int tc = t - 8;
                    if (tc < 1) tc = 1;
                    A0[r] = *reinterpret_cast<const float4*>(&ap[(size_t)tc * 64 + st * 8]);
                    A1[r] = *reinterpret_cast<const float4*>(&ap[(size_t)tc * 64 + st * 8 + 4]);
                    beR[r] = be[(size_t)tc * 8 + st];
                }
                beta = fb_matvecT(a0, a1, w);
                if (lane < 8) bwdS[t - 1][lane] = beta;
                if (r == 3 || r == 7) {
                    float s4 = gsum8(beta);
                    beta *= __builtin_amdgcn_rcpf(s4);
                }
            }
        }
#pragma unroll
        for (int r = 0; r < 7; ++r) {
            const int t = 7 - r;
            float4 a0 = A0[r], a1 = A1[r];
            float w = beta * beR[r];
            beta = fb_matvecT(a0, a1, w);
            if (lane < 8) bwdS[t - 1][lane] = beta;
            if (r == 3) {
                float s4 = gsum8(beta);
                beta *= __builtin_amdgcn_rcpf(s4);
            }
        }
    }
    __syncthreads();
    for (int t = tid; t < NT; t += 128) {
        float lg[8], ssum = 0.f;
#pragma unroll
        for (int q = 0; q < 8; ++q) {
            lg[q] = fwdS[t][q] * bwdS[t][q];
            ssum += lg[q];
        }
        float inv = __builtin_amdgcn_rcpf(ssum);
#pragma unroll
        for (int q = 0; q < 8; ++q)
            gamma[((size_t)b * NT + t) * 8 + q] = lg[q] * inv;
    }
}

// ---------------------------------------------------------------------------
// K6: emission + reduction
// ---------------------------------------------------------------------------
__global__ __launch_bounds__(256) void k_emit(
    const float* __restrict__ ys, const float* __restrict__ x,
    const float* __restrict__ means, const float* __restrict__ gamma,
    const float* __restrict__ C, const float* __restrict__ dvec,
    const float* __restrict__ y_logvar, const float* __restrict__ xent,
    float* __restrict__ red)
{
    __shared__ float xg[8][32];
    __shared__ float gs[8][8];
    __shared__ float wsum[8][4];
    const int tid = threadIdx.x;
    const int itemBase = blockIdx.x * 8;
    const int b = itemBase >> 10;
    const int t0 = itemBase & (NT - 1);
    if (tid < 64) {
        int it = tid >> 3, q = tid & 7;
        if (t0 + it > 0)
            gs[it][q] = gamma[((size_t)itemBase + it) * 8 + q];
    }
    __syncthreads();
    {
        int it = tid >> 5, xo = tid & 31;
        int t = t0 + it;
        float v;
        if (t == 0) {
            v = x[((size_t)itemBase + it) * 32 + xo];
        } else {
            const float* mp = &means[(((size_t)b * 1023 + (t - 1)) * 8) * 32 + xo];
            v = 0.f;
#pragma unroll
            for (int q = 0; q < 8; ++q) v = fmaf(mp[q * 32], gs[it][q], v);
        }
        xg[it][xo] = v;
    }
    __syncthreads();
    float acc[8][2] = {};
    for (int e = 0; e < 32; ++e) {
        float c0 = C[e * 512 + tid];
        float c1 = C[e * 512 + tid + 256];
#pragma unroll
        for (int it = 0; it < 8; ++it) {
            float xv = xg[it][e];
            acc[it][0] = fmaf(xv, c0, acc[it][0]);
            acc[it][1] = fmaf(xv, c1, acc[it][1]);
        }
    }
    float d0 = dvec[tid], d1 = dvec[tid + 256];
    float ylv0 = y_logvar[tid], ylv1 = y_logvar[tid + 256];
    float iv0 = expf(-ylv0), iv1 = expf(-ylv1);
    float base0 = ylv0 + LOG2PI, base1 = ylv1 + LOG2PI;
#pragma unroll
    for (int it = 0; it < 8; ++it) {
        const float* yrow = &ys[((size_t)itemBase + it) * 512];
        float df0 = yrow[tid] - (acc[it][0] + d0);
        float df1 = yrow[tid + 256] - (acc[it][1] + d1);
        float lsum = -0.5f * (df0 * df0 * iv0 + base0)
                   - 0.5f * (df1 * df1 * iv1 + base1);
#pragma unroll
        for (int m = 1; m < 64; m <<= 1) lsum += __shfl_xor(lsum, m, 64);
        if ((tid & 63) == 0) wsum[it][tid >> 6] = lsum;
    }
    __syncthreads();
    if (tid < 8)
        red[itemBase + tid] = wsum[tid][0] + wsum[tid][1] + wsum[tid][2]
                            + wsum[tid][3] + xent[itemBase + tid];
}

__global__ __launch_bounds__(256) void k_final(
    const float* __restrict__ red, const float* __restrict__ log_px,
    float* __restrict__ out)
{
    __shared__ float ssum[4];
    float s = 0.f;
    for (int i = threadIdx.x; i < NB * NT; i += 256) s += red[i];
    if (threadIdx.x < NB) s += log_px[threadIdx.x];
#pragma unroll
    for (int m = 1; m < 64; m <<= 1) s += __shfl_xor(s, m, 64);
    if ((threadIdx.x & 63) == 0) ssum[threadIdx.x >> 6] = s;
    __syncthreads();
    if (threadIdx.x == 0)
        out[0] = (ssum[0] + ssum[1] + ssum[2] + ssum[3]) / (float)NB;
}

// ---------------------------------------------------------------------------
extern "C" void kernel_launch(void* const* d_in, const int* in_sizes, int n_in,
                              void* d_out, int out_size, void* d_ws,
                              size_t ws_size, hipStream_t stream)
{
    const float* ys        = (const float*)d_in[0];
    const float* us        = (const float*)d_in[1];
    const float* eps       = (const float*)d_in[2];
    const float* W1        = (const float*)d_in[3];
    const float* b1        = (const float*)d_in[4];
    const float* Wmu       = (const float*)d_in[5];
    const float* bmu       = (const float*)d_in[6];
    const float* Wlv       = (const float*)d_in[7];
    const float* blv       = (const float*)d_in[8];
    const float* Wz        = (const float*)d_in[9];
    const float* bz        = (const float*)d_in[10];
    const float* A         = (const float*)d_in[11];
    const float* Bu        = (const float*)d_in[12];
    const float* bx        = (const float*)d_in[13];
    const float* x_logvar  = (const float*)d_in[14];
    const float* x0_mean   = (const float*)d_in[15];
    const float* x0_logvar = (const float*)d_in[16];
    const float* C         = (const float*)d_in[17];
    const float* dv        = (const float*)d_in[18];
    const float* y_logvar  = (const float*)d_in[19];
    const float* log_init_z= (const float*)d_in[20];
    float* out = (float*)d_out;

    float* ws = (float*)d_ws;
    float* hbf_f  = ws;                    //  8,388,608 (h bf16)
    float* x      = hbf_f + 8388608;       //  1,048,576
    float* xent   = x + 1048576;           //     32,768
    float* ap1    = xent + 32768;          //  2,097,152
    float* bexp   = ap1 + 2097152;         //    262,144
    float* log_b  = bexp + 262144;         //    262,144
    float* means  = log_b + 262144;        //  8,380,416
    float* gam    = means + 8380416;       //    262,144
    float* log_px = gam + 262144;          //         32
    float* mbsum  = log_px + 32;           //         32
    float* red    = mbsum + 32;            //     32,768
    float* w1t_f  = red + 32768;           //    131,072 (W1^T bf16)
    float* wmlv_f = w1t_f + 131072;        //     16,384 (Wmu|Wlv^T bf16)

    unsigned short* hbf  = (unsigned short*)hbf_f;
    unsigned short* w1t  = (unsigned short*)w1t_f;
    unsigned short* wmlv = (unsigned short*)wmlv_f;

    k_castT    <<<dim3(16, 16), 256, 0, stream>>>(W1, w1t);
    k_cast_mulv<<<dim3(16, 2), 256, 0, stream>>>(Wmu, Wlv, wmlv);
    k_gemm_h_mfma<<<dim3(4, 256), 256, 0, stream>>>(ys, w1t, b1, hbf);
    k_mulv_mfma<<<256, 256, 0, stream>>>(hbf, wmlv, bmu, blv, eps, x, xent);
    k_loga <<<8192, 256, 0, stream>>>(x, Wz, bz, ap1);
    k_means<<<32 * 1023, 256, 0, stream>>>(x, us, A, Bu, bx, x_logvar, means, log_b);
    k_logb0<<<32, 256, 0, stream>>>(x, x0_mean, x0_logvar, log_b);
    k_prep <<<32, 256, 0, stream>>>(log_b, bexp, mbsum);
    k_fb   <<<32, 128, 0, stream>>>(ap1, bexp, mbsum, log_init_z, gam, log_px);
    k_emit <<<4096, 256, 0, stream>>>(ys, x, means, gam, C, dv, y_logvar, xent, red);
    k_final<<<1, 256, 0, stream>>>(red, log_px, out);
}

// Round 5
// 320.406 us; speedup vs baseline: 4.0487x; 1.1834x over previous
//
#include <hip/hip_runtime.h>
#include <math.h>

#define LOG2PI 1.8378770664093453f

// Problem sizes (fixed)
#define NB 32
#define NT 1024
#define ND 512
#define NH 512
#define NX 32
#define NK 8
#define NU 2

typedef __attribute__((ext_vector_type(8))) short bf16x8;
typedef __attribute__((ext_vector_type(4))) float f32x4;

__device__ __forceinline__ unsigned short f2bf(float f) {
    unsigned u = __float_as_uint(f);
    unsigned r = (u + 0x7FFF + ((u >> 16) & 1)) >> 16;
    return (unsigned short)r;
}

// ---------------------------------------------------------------------------
// DPP xor-shuffles within 8-lane groups (VALU pipe, no LDS latency)
// ---------------------------------------------------------------------------
#define DPP_X1 0xB1
#define DPP_X2 0x4E
#define DPP_X3 0x1B
#define DPP_X7 0x141

template <int CTRL>
__device__ __forceinline__ float dppx(float v) {
    return __int_as_float(__builtin_amdgcn_update_dpp(
        0, __float_as_int(v), CTRL, 0xF, 0xF, true));
}

// alpha' = A * alpha (xor-factorized; row in a0|a1, alpha replicated per 8)
__device__ __forceinline__ float fb_matvec(float4 a0, float4 a1, float v) {
    float p1 = dppx<DPP_X1>(v);
    float p2 = dppx<DPP_X2>(v);
    float p3 = dppx<DPP_X3>(v);
    float p7 = dppx<DPP_X7>(v);
    float p4 = dppx<DPP_X7>(p3);
    float p5 = dppx<DPP_X7>(p2);
    float p6 = dppx<DPP_X7>(p1);
    float c0 = fmaf(a0.y, p1, a0.x * v);
    float c1 = fmaf(a0.w, p3, a0.z * p2);
    float c2 = fmaf(a1.y, p5, a1.x * p4);
    float c3 = fmaf(a1.w, p7, a1.z * p6);
    return (c0 + c1) + (c2 + c3);
}

// beta' = A^T * w using the SAME ap1 rows
__device__ __forceinline__ float fb_matvecT(float4 a0, float4 a1, float w) {
    float q0 = a0.x * w;
    float t1 = dppx<DPP_X1>(a0.y * w);
    float t2 = dppx<DPP_X2>(a0.z * w);
    float t3 = dppx<DPP_X3>(a0.w * w);
    float t7 = dppx<DPP_X7>(a1.w * w);
    float t4 = dppx<DPP_X7>(dppx<DPP_X3>(a1.x * w));
    float t5 = dppx<DPP_X7>(dppx<DPP_X2>(a1.y * w));
    float t6 = dppx<DPP_X7>(dppx<DPP_X1>(a1.z * w));
    return ((q0 + t1) + (t2 + t3)) + ((t4 + t5) + (t6 + t7));
}

// sum over the 8-lane group (replicated result)
__device__ __forceinline__ float gsum8(float v) {
    float s = v + dppx<DPP_X1>(v);
    s = s + dppx<DPP_X2>(s);
    s = s + dppx<DPP_X7>(dppx<DPP_X3>(s));
    return s;
}

__device__ __forceinline__ float lse8_high(float v) {
    float m = v;
    m = fmaxf(m, __shfl_xor(m, 8, 64));
    m = fmaxf(m, __shfl_xor(m, 16, 64));
    m = fmaxf(m, __shfl_xor(m, 32, 64));
    float s = expf(v - m);
    s += __shfl_xor(s, 8, 64);
    s += __shfl_xor(s, 16, 64);
    s += __shfl_xor(s, 32, 64);
    return m + logf(s);
}

// ---------------------------------------------------------------------------
// W1 [K=512][N=512] f32 -> W1T [N][K] bf16
// ---------------------------------------------------------------------------
__global__ __launch_bounds__(256) void k_castT(
    const float* __restrict__ W, unsigned short* __restrict__ WT)
{
    __shared__ float tile[32][33];
    const int bx = blockIdx.x * 32;
    const int by = blockIdx.y * 32;
    const int tx = threadIdx.x & 31, ty = threadIdx.x >> 5;
    for (int i = ty; i < 32; i += 8)
        tile[i][tx] = W[(size_t)(bx + i) * 512 + by + tx];
    __syncthreads();
    for (int i = ty; i < 32; i += 8)
        WT[(size_t)(by + i) * 512 + bx + tx] = f2bf(tile[tx][i]);
}

// Wmu/Wlv [512][32] f32 -> out [64][512] bf16
__global__ __launch_bounds__(256) void k_cast_mulv(
    const float* __restrict__ Wmu, const float* __restrict__ Wlv,
    unsigned short* __restrict__ out)
{
    __shared__ float tile[32][33];
    const float* W = blockIdx.y ? Wlv : Wmu;
    const int base = blockIdx.y * 32;
    const int g = blockIdx.x;
    const int tx = threadIdx.x & 31, ty = threadIdx.x >> 5;
    for (int i = ty; i < 32; i += 8)
        tile[i][tx] = W[(size_t)(g * 32 + i) * 32 + tx];
    __syncthreads();
    for (int i = ty; i < 32; i += 8)
        out[(size_t)(base + i) * 512 + g * 32 + tx] = f2bf(tile[tx][i]);
}

// ---------------------------------------------------------------------------
// prep for emission factorization: ivbuf = exp(-ylv), term0 = sum(ylv+LOG2PI)
// ---------------------------------------------------------------------------
__global__ __launch_bounds__(256) void k_prepc1(
    const float* __restrict__ ylv, float* __restrict__ ivbuf,
    float* __restrict__ term0)
{
    __shared__ float part[256];
    const int tid = threadIdx.x;
    float s = 0.f;
    for (int i = tid; i < 512; i += 256) {
        float lv = ylv[i];
        ivbuf[i] = expf(-lv);
        s += lv + LOG2PI;
    }
    part[tid] = s;
    __syncthreads();
    for (int st = 128; st; st >>= 1) {
        if (tid < st) part[tid] += part[tid + st];
        __syncthreads();
    }
    if (tid == 0) term0[0] = part[0];
}

// blocks 0-31: G[x][y] = sum_d C[x,d]*iv_d*C[y,d] (pad 33) + c2x[x]
// block 32: W2bf[x][d] = bf16(iv_d * C[x,d])
__global__ __launch_bounds__(256) void k_prepc2(
    const float* __restrict__ C, const float* __restrict__ dvec,
    const float* __restrict__ ivbuf, unsigned short* __restrict__ W2bf,
    float* __restrict__ G, float* __restrict__ c2x)
{
    const int x = blockIdx.x;
    const int tid = threadIdx.x;
    if (x == 32) {
        for (int i = tid; i < 32 * 512; i += 256)
            W2bf[i] = f2bf(C[i] * ivbuf[i & 511]);
        return;
    }
    const int y = tid >> 3, seg = tid & 7;
    const float* Cx = &C[(size_t)x * 512];
    const float* Cy = &C[(size_t)y * 512];
    float p = 0.f;
    for (int j = 0; j < 64; ++j) {
        int dcol = seg * 64 + j;
        p = fmaf(Cx[dcol] * ivbuf[dcol], Cy[dcol], p);
    }
    p = gsum8(p);
    if (seg == 0) G[x * 33 + y] = p;
    if (tid < 8) {
        float q = 0.f;
        for (int j = 0; j < 64; ++j) {
            int dcol = tid * 64 + j;
            q = fmaf(Cx[dcol] * ivbuf[dcol], dvec[dcol], q);
        }
        q = gsum8(q);
        if (tid == 0) c2x[x] = q;
    }
}

// ---------------------------------------------------------------------------
// K1: h_bf = bf16(tanh(ys @ W1 + b1)). Reads f32 ys, casts in-register.
// ---------------------------------------------------------------------------
__global__ __launch_bounds__(256) void k_gemm_h_mfma(
    const float* __restrict__ ys,
    const unsigned short* __restrict__ Bbf,
    const float* __restrict__ b1, unsigned short* __restrict__ hb)
{
    __shared__ unsigned short As[128 * 64];
    __shared__ unsigned short Bs[128 * 64];
    const int tid = threadIdx.x;
    const int bm = blockIdx.y * 128;
    const int bn = blockIdx.x * 128;
    const int wid = tid >> 6, lane = tid & 63;
    const int wm = wid >> 1, wn = wid & 1;

    f32x4 acc[4][4];
#pragma unroll
    for (int m = 0; m < 4; ++m)
#pragma unroll
        for (int n = 0; n < 4; ++n)
            acc[m][n] = (f32x4){0.f, 0.f, 0.f, 0.f};

    for (int k0 = 0; k0 < 512; k0 += 64) {
#pragma unroll
        for (int r = 0; r < 4; ++r) {
            int l = tid + r * 256;
            int row = l >> 3, c8 = l & 7;
            int sidx = row * 8 + (c8 ^ (row & 7));
            const float4 f0 = *reinterpret_cast<const float4*>(
                &ys[(size_t)(bm + row) * 512 + k0 + c8 * 8]);
            const float4 f1 = *reinterpret_cast<const float4*>(
                &ys[(size_t)(bm + row) * 512 + k0 + c8 * 8 + 4]);
            uint4 ua;
            ua.x = (unsigned)f2bf(f0.x) | ((unsigned)f2bf(f0.y) << 16);
            ua.y = (unsigned)f2bf(f0.z) | ((unsigned)f2bf(f0.w) << 16);
            ua.z = (unsigned)f2bf(f1.x) | ((unsigned)f2bf(f1.y) << 16);
            ua.w = (unsigned)f2bf(f1.z) | ((unsigned)f2bf(f1.w) << 16);
            *reinterpret_cast<uint4*>(&As[sidx * 8]) = ua;
            uint4 vb = *reinterpret_cast<const uint4*>(
                &Bbf[(size_t)(bn + row) * 512 + k0 + c8 * 8]);
            *reinterpret_cast<uint4*>(&Bs[sidx * 8]) = vb;
        }
        __syncthreads();
#pragma unroll
        for (int kh = 0; kh < 2; ++kh) {
            bf16x8 af[4], bfr[4];
            const int c8r = kh * 4 + (lane >> 4);
#pragma unroll
            for (int m = 0; m < 4; ++m) {
                int rA = wm * 64 + m * 16 + (lane & 15);
                af[m] = *reinterpret_cast<bf16x8*>(
                    &As[rA * 64 + (c8r ^ (rA & 7)) * 8]);
            }
#pragma unroll
            for (int n = 0; n < 4; ++n) {
                int rB = wn * 64 + n * 16 + (lane & 15);
                bfr[n] = *reinterpret_cast<bf16x8*>(
                    &Bs[rB * 64 + (c8r ^ (rB & 7)) * 8]);
            }
#pragma unroll
            for (int m = 0; m < 4; ++m)
#pragma unroll
                for (int n = 0; n < 4; ++n)
                    acc[m][n] = __builtin_amdgcn_mfma_f32_16x16x32_bf16(
                        af[m], bfr[n], acc[m][n], 0, 0, 0);
        }
        __syncthreads();
    }
    float b1v[4];
#pragma unroll
    for (int n = 0; n < 4; ++n)
        b1v[n] = b1[bn + wn * 64 + n * 16 + (lane & 15)];
#pragma unroll
    for (int m = 0; m < 4; ++m) {
#pragma unroll
        for (int q = 0; q < 4; ++q) {
            int row = bm + wm * 64 + m * 16 + (lane >> 4) * 4 + q;
#pragma unroll
            for (int n = 0; n < 4; ++n) {
                int col = bn + wn * 64 + n * 16 + (lane & 15);
                hb[(size_t)row * 512 + col] = f2bf(tanhf(acc[m][n][q] + b1v[n]));
            }
        }
    }
}

// ---------------------------------------------------------------------------
// K2: [mu|lv] = h_bf @ Wt^T via MFMA; epilogue fuses x, xent
// ---------------------------------------------------------------------------
__global__ __launch_bounds__(256) void k_mulv_mfma(
    const unsigned short* __restrict__ hbf,
    const unsigned short* __restrict__ Wt,
    const float* __restrict__ bmu, const float* __restrict__ blv,
    const float* __restrict__ eps,
    float* __restrict__ x, float* __restrict__ xent)
{
    __shared__ unsigned short As[128 * 64];
    __shared__ unsigned short Bs[64 * 64];
    const int tid = threadIdx.x;
    const int bm = blockIdx.x * 128;
    const int wid = tid >> 6, lane = tid & 63;
    f32x4 acc[2][4];
#pragma unroll
    for (int m = 0; m < 2; ++m)
#pragma unroll
        for (int n = 0; n < 4; ++n)
            acc[m][n] = (f32x4){0.f, 0.f, 0.f, 0.f};

    for (int k0 = 0; k0 < 512; k0 += 64) {
#pragma unroll
        for (int r = 0; r < 4; ++r) {
            int l = tid + r * 256, row = l >> 3, c8 = l & 7;
            int sidx = row * 8 + (c8 ^ (row & 7));
            uint4 v = *reinterpret_cast<const uint4*>(
                &hbf[(size_t)(bm + row) * 512 + k0 + c8 * 8]);
            *reinterpret_cast<uint4*>(&As[sidx * 8]) = v;
        }
#pragma unroll
        for (int r = 0; r < 2; ++r) {
            int l = tid + r * 256, row = l >> 3, c8 = l & 7;
            int sidx = row * 8 + (c8 ^ (row & 7));
            uint4 v = *reinterpret_cast<const uint4*>(
                &Wt[(size_t)row * 512 + k0 + c8 * 8]);
            *reinterpret_cast<uint4*>(&Bs[sidx * 8]) = v;
        }
        __syncthreads();
#pragma unroll
        for (int kh = 0; kh < 2; ++kh) {
            const int c8r = kh * 4 + (lane >> 4);
            bf16x8 af[2], bfr[4];
#pragma unroll
            for (int m = 0; m < 2; ++m) {
                int rA = wid * 32 + m * 16 + (lane & 15);
                af[m] = *reinterpret_cast<bf16x8*>(
                    &As[rA * 64 + (c8r ^ (rA & 7)) * 8]);
            }
#pragma unroll
            for (int n = 0; n < 4; ++n) {
                int rB = n * 16 + (lane & 15);
                bfr[n] = *reinterpret_cast<bf16x8*>(
                    &Bs[rB * 64 + (c8r ^ (rB & 7)) * 8]);
            }
#pragma unroll
            for (int m = 0; m < 2; ++m)
#pragma unroll
                for (int n = 0; n < 4; ++n)
                    acc[m][n] = __builtin_amdgcn_mfma_f32_16x16x32_bf16(
                        af[m], bfr[n], acc[m][n], 0, 0, 0);
        }
        __syncthreads();
    }
    const int o0 = lane & 15, o1 = 16 + (lane & 15);
    const float bm0 = bmu[o0], bm1 = bmu[o1];
    const float bl0 = blv[o0], bl1 = blv[o1];
#pragma unroll
    for (int m = 0; m < 2; ++m) {
#pragma unroll
        for (int q = 0; q < 4; ++q) {
            int row = bm + wid * 32 + m * 16 + (lane >> 4) * 4 + q;
            float mu0 = acc[m][0][q] + bm0;
            float mu1 = acc[m][1][q] + bm1;
            float lv0 = acc[m][2][q] + bl0;
            float lv1 = acc[m][3][q] + bl1;
            float e0 = eps[(size_t)row * 32 + o0];
            float e1 = eps[(size_t)row * 32 + o1];
            x[(size_t)row * 32 + o0] = mu0 + expf(0.5f * lv0) * e0;
            x[(size_t)row * 32 + o1] = mu1 + expf(0.5f * lv1) * e1;
            float pe = (e0 * e0 + lv0) + (e1 * e1 + lv1);
            pe += __shfl_xor(pe, 1, 64);
            pe += __shfl_xor(pe, 2, 64);
            pe += __shfl_xor(pe, 4, 64);
            pe += __shfl_xor(pe, 8, 64);
            if ((lane & 15) == 0)
                xent[row] = 0.5f * (pe + 32.f * LOG2PI);
        }
    }
}

// ---------------------------------------------------------------------------
// K2b: proj = ys @ W2bf^T (M=32768, N=32, K=512) + term1 from f32 ys.
// ---------------------------------------------------------------------------
__global__ __launch_bounds__(256) void k_proj(
    const float* __restrict__ ys, const unsigned short* __restrict__ W2bf,
    const float* __restrict__ dvec, const float* __restrict__ ivbuf,
    float* __restrict__ proj, float* __restrict__ term1)
{
    __shared__ unsigned short As[128 * 64];
    __shared__ unsigned short Bs[32 * 64];
    const int tid = threadIdx.x;
    const int bm = blockIdx.x * 128;
    const int wid = tid >> 6, lane = tid & 63;
    const int c8 = tid & 7;
    f32x4 acc[2][2];
#pragma unroll
    for (int m = 0; m < 2; ++m)
#pragma unroll
        for (int n = 0; n < 2; ++n)
            acc[m][n] = (f32x4){0.f, 0.f, 0.f, 0.f};
    float t1p[4] = {0.f, 0.f, 0.f, 0.f};

    for (int k0 = 0; k0 < 512; k0 += 64) {
        const float4 dv0 = *reinterpret_cast<const float4*>(&dvec[k0 + c8 * 8]);
        const float4 dv1 = *reinterpret_cast<const float4*>(&dvec[k0 + c8 * 8 + 4]);
        const float4 iv0 = *reinterpret_cast<const float4*>(&ivbuf[k0 + c8 * 8]);
        const float4 iv1 = *reinterpret_cast<const float4*>(&ivbuf[k0 + c8 * 8 + 4]);
#pragma unroll
        for (int r = 0; r < 4; ++r) {
            int l = tid + r * 256;
            int row = l >> 3;
            int sidx = row * 8 + (c8 ^ (row & 7));
            const float4 f0 = *reinterpret_cast<const float4*>(
                &ys[(size_t)(bm + row) * 512 + k0 + c8 * 8]);
            const float4 f1 = *reinterpret_cast<const float4*>(
                &ys[(size_t)(bm + row) * 512 + k0 + c8 * 8 + 4]);
            float g0 = f0.x - dv0.x, g1 = f0.y - dv0.y;
            float g2 = f0.z - dv0.z, g3 = f0.w - dv0.w;
            float g4 = f1.x - dv1.x, g5 = f1.y - dv1.y;
            float g6 = f1.z - dv1.z, g7 = f1.w - dv1.w;
            t1p[r] += (g0 * g0 * iv0.x + g1 * g1 * iv0.y)
                    + (g2 * g2 * iv0.z + g3 * g3 * iv0.w)
                    + (g4 * g4 * iv1.x + g5 * g5 * iv1.y)
                    + (g6 * g6 * iv1.z + g7 * g7 * iv1.w);
            uint4 ua;
            ua.x = (unsigned)f2bf(f0.x) | ((unsigned)f2bf(f0.y) << 16);
            ua.y = (unsigned)f2bf(f0.z) | ((unsigned)f2bf(f0.w) << 16);
            ua.z = (unsigned)f2bf(f1.x) | ((unsigned)f2bf(f1.y) << 16);
            ua.w = (unsigned)f2bf(f1.z) | ((unsigned)f2bf(f1.w) << 16);
            *reinterpret_cast<uint4*>(&As[sidx * 8]) = ua;
        }
        {
            int row = tid >> 3;
            int sidx = row * 8 + (c8 ^ (row & 7));
            uint4 v = *reinterpret_cast<const uint4*>(
                &W2bf[(size_t)row * 512 + k0 + c8 * 8]);
            *reinterpret_cast<uint4*>(&Bs[sidx * 8]) = v;
        }
        __syncthreads();
#pragma unroll
        for (int kh = 0; kh < 2; ++kh) {
            const int c8r = kh * 4 + (lane >> 4);
            bf16x8 af[2], bfr[2];
#pragma unroll
            for (int m = 0; m < 2; ++m) {
                int rA = wid * 32 + m * 16 + (lane & 15);
                af[m] = *reinterpret_cast<bf16x8*>(
                    &As[rA * 64 + (c8r ^ (rA & 7)) * 8]);
            }
#pragma unroll
            for (int n = 0; n < 2; ++n) {
                int rB = n * 16 + (lane & 15);
                bfr[n] = *reinterpret_cast<bf16x8*>(
                    &Bs[rB * 64 + (c8r ^ (rB & 7)) * 8]);
            }
#pragma unroll
            for (int m = 0; m < 2; ++m)
#pragma unroll
                for (int n = 0; n < 2; ++n)
                    acc[m][n] = __builtin_amdgcn_mfma_f32_16x16x32_bf16(
                        af[m], bfr[n], acc[m][n], 0, 0, 0);
        }
        __syncthreads();
    }
#pragma unroll
    for (int m = 0; m < 2; ++m)
#pragma unroll
        for (int q = 0; q < 4; ++q) {
            int row = bm + wid * 32 + m * 16 + (lane >> 4) * 4 + q;
#pragma unroll
            for (int n = 0; n < 2; ++n) {
                int col = n * 16 + (lane & 15);
                proj[(size_t)row * 32 + col] = acc[m][n][q];
            }
        }
#pragma unroll
    for (int r = 0; r < 4; ++r) {
        float s = gsum8(t1p[r]);
        if ((tid & 7) == 0) term1[bm + (tid >> 3) + r * 32] = s;
    }
}

// ---------------------------------------------------------------------------
// K3: softmax_j(x[b,t-1] @ Wz + bz) -> ap1[t][s][e] = a[s][s^e]
// ---------------------------------------------------------------------------
__global__ __launch_bounds__(256) void k_loga(
    const float* __restrict__ x, const float* __restrict__ Wz,
    const float* __restrict__ bz, float* __restrict__ ap1)
{
    const int tid = threadIdx.x;
    const int item = blockIdx.x * 4 + (tid >> 6);
    const int lane = tid & 63;
    const int t = item & (NT - 1);
    if (t == 0) return;
    const int j = lane >> 3, k = lane & 7;
    const float* xr = &x[((size_t)item - 1) * 32];
    float acc = bz[lane];
#pragma unroll
    for (int e = 0; e < 32; ++e) acc = fmaf(xr[e], Wz[e * 64 + lane], acc);
    float lse = lse8_high(acc);
    ap1[(size_t)item * 64 + j * 8 + (j ^ k)] = expf(acc - lse);
}

// ---------------------------------------------------------------------------
// K4: means + log_b
// ---------------------------------------------------------------------------
__global__ __launch_bounds__(256) void k_means(
    const float* __restrict__ x, const float* __restrict__ us,
    const float* __restrict__ A, const float* __restrict__ Bu,
    const float* __restrict__ bx, const float* __restrict__ x_logvar,
    float* __restrict__ means, float* __restrict__ log_b)
{
    __shared__ float xs[32];
    __shared__ float uu[2];
    const int item = blockIdx.x;
    const int b = item / 1023;
    const int tm = item - b * 1023;
    const int tid = threadIdx.x;
    const int k = tid >> 5, xo = tid & 31;
    if (tid < 32) xs[tid] = x[((size_t)b * NT + tm) * 32 + tid];
    if (tid < 2) uu[tid] = us[((size_t)b * NT + tm + 1) * 2 + tid];
    __syncthreads();
    float acc = bx[k * 32 + xo];
#pragma unroll
    for (int e = 0; e < 32; ++e)
        acc = fmaf(xs[e], A[((size_t)k * 32 + e) * 32 + xo], acc);
    acc = fmaf(uu[0], Bu[((size_t)k * 2 + 0) * 32 + xo], acc);
    acc = fmaf(uu[1], Bu[((size_t)k * 2 + 1) * 32 + xo], acc);
    means[((size_t)item * 8 + k) * 32 + xo] = acc;
    float xv = x[((size_t)b * NT + tm + 1) * 32 + xo];
    float lvv = x_logvar[k * 32 + xo];
    float dd = xv - acc;
    float term = -0.5f * (dd * dd * expf(-lvv) + lvv + LOG2PI);
    for (int m = 16; m; m >>= 1) term += __shfl_down(term, m, 32);
    if (xo == 0) log_b[((size_t)b * NT + tm + 1) * 8 + k] = term;
}

__global__ __launch_bounds__(256) void k_logb0(
    const float* __restrict__ x, const float* __restrict__ x0_mean,
    const float* __restrict__ x0_logvar, float* __restrict__ log_b)
{
    const int b = blockIdx.x;
    const int tid = threadIdx.x;
    const int k = tid >> 5, xo = tid & 31;
    float xv = x[((size_t)b * NT) * 32 + xo];
    float mm = x0_mean[k * 32 + xo];
    float lvv = x0_logvar[k * 32 + xo];
    float dd = xv - mm;
    float term = -0.5f * (dd * dd * expf(-lvv) + lvv + LOG2PI);
    for (int m = 16; m; m >>= 1) term += __shfl_down(term, m, 32);
    if (xo == 0) log_b[(size_t)b * NT * 8 + k] = term;
}

// ---------------------------------------------------------------------------
// K4c: bexp/mbsum prep for the scan
// ---------------------------------------------------------------------------
__global__ __launch_bounds__(256) void k_prep(
    const float* __restrict__ log_b, float* __restrict__ bexp,
    float* __restrict__ mbsum)
{
    __shared__ float part[256];
    const int b = blockIdx.x;
    const int tid = threadIdx.x;
    float msum = 0.f;
    for (int t = tid; t < NT; t += 256) {
        const float* lbp = &log_b[((size_t)b * NT + t) * 8];
        float4 l0 = *reinterpret_cast<const float4*>(lbp);
        float4 l1 = *reinterpret_cast<const float4*>(lbp + 4);
        float mm = fmaxf(fmaxf(fmaxf(l0.x, l0.y), fmaxf(l0.z, l0.w)),
                         fmaxf(fmaxf(l1.x, l1.y), fmaxf(l1.z, l1.w)));
        float4 e0, e1;
        e0.x = expf(l0.x - mm); e0.y = expf(l0.y - mm);
        e0.z = expf(l0.z - mm); e0.w = expf(l0.w - mm);
        e1.x = expf(l1.x - mm); e1.y = expf(l1.y - mm);
        e1.z = expf(l1.z - mm); e1.w = expf(l1.w - mm);
        float* bp = &bexp[((size_t)b * NT + t) * 8];
        *reinterpret_cast<float4*>(bp) = e0;
        *reinterpret_cast<float4*>(bp + 4) = e1;
        msum += mm;
    }
    part[tid] = msum;
    __syncthreads();
    for (int s = 128; s; s >>= 1) {
        if (tid < s) part[tid] += part[tid + s];
        __syncthreads();
    }
    if (tid == 0) mbsum[b] = part[0];
}

// ---------------------------------------------------------------------------
// K5: forward-backward, scaled linear space, DPP-only cross-lane.
// ---------------------------------------------------------------------------
__global__ __launch_bounds__(128) void k_fb(
    const float* __restrict__ ap1, const float* __restrict__ bexp,
    const float* __restrict__ mbsum, const float* __restrict__ log_init_z,
    float* __restrict__ gamma, float* __restrict__ log_px)
{
    __shared__ float fwdS[NT][8];
    __shared__ float bwdS[NT][8];
    const int b = blockIdx.x;
    const int tid = threadIdx.x;
    const int wave = tid >> 6;
    const int lane = tid & 63;
    const int st = lane & 7;
    const float* ap = &ap1[(size_t)b * NT * 64];
    const float* be = &bexp[(size_t)b * NT * 8];

    float4 A0[8], A1[8];
    float beR[8];

    if (wave == 0) {
        float mz = -1e30f, sz = 0.f;
        float liv[8];
#pragma unroll
        for (int q = 0; q < 8; ++q) liv[q] = log_init_z[q];
#pragma unroll
        for (int q = 0; q < 8; ++q) mz = fmaxf(mz, liv[q]);
#pragma unroll
        for (int q = 0; q < 8; ++q) sz += expf(liv[q] - mz);
        float alpha = (expf(liv[st] - mz) / sz) * be[st];
        float logS = 0.f;
        if (lane < 8) fwdS[0][lane] = alpha;
#pragma unroll
        for (int r = 0; r < 8; ++r) {
            int tc = 1 + r;
            A0[r] = *reinterpret_cast<const float4*>(&ap[(size_t)tc * 64 + st * 8]);
            A1[r] = *reinterpret_cast<const float4*>(&ap[(size_t)tc * 64 + st * 8 + 4]);
            beR[r] = be[(size_t)tc * 8 + st];
        }
        for (int tb = 1; tb <= 1009; tb += 8) {
#pragma unroll
            for (int r = 0; r < 8; ++r) {
                const int t = tb + r;
                float4 a0 = A0[r], a1 = A1[r];
                float bv = beR[r];
                {
                    int tc = t + 8;
                    if (tc > NT - 1) tc = NT - 1;
                    A0[r] = *reinterpret_cast<const float4*>(&ap[(size_t)tc * 64 + st * 8]);
                    A1[r] = *reinterpret_cast<const float4*>(&ap[(size_t)tc * 64 + st * 8 + 4]);
                    beR[r] = be[(size_t)tc * 8 + st];
                }
                alpha = fb_matvec(a0, a1, alpha) * bv;
                if (lane < 8) fwdS[t][lane] = alpha;
                if (r == 2 || r == 6) {
                    float s4 = gsum8(alpha);
                    logS += __logf(s4);
                    alpha *= __builtin_amdgcn_rcpf(s4);
                }
            }
        }
#pragma unroll
        for (int r = 0; r < 7; ++r) {
            const int t = 1017 + r;
            float4 a0 = A0[r], a1 = A1[r];
            float bv = beR[r];
            alpha = fb_matvec(a0, a1, alpha) * bv;
            if (lane < 8) fwdS[t][lane] = alpha;
            if (r == 2 || r == 6) {
                float s4 = gsum8(alpha);
                logS += __logf(s4);
                alpha *= __builtin_amdgcn_rcpf(s4);
            }
        }
        float s4 = gsum8(alpha);
        if (lane == 0) log_px[b] = mbsum[b] + logS + __logf(s4);
    } else {
        float beta = 1.f;
        if (lane < 8) bwdS[NT - 1][lane] = 1.f;
#pragma unroll
        for (int r = 0; r < 8; ++r) {
            int tc = 1023 - r;
            A0[r] = *reinterpret_cast<const float4*>(&ap[(size_t)tc * 64 + st * 8]);
            A1[r] = *reinterpret_cast<const float4*>(&ap[(size_t)tc * 64 + st * 8 + 4]);
            beR[r] = be[(size_t)tc * 8 + st];
        }
        for (int tb = 1023; tb >= 15; tb -= 8) {
#pragma unroll
            for (int r = 0; r < 8; ++r) {
                const int t = tb - r;
                float4 a0 = A0[r], a1 = A1[r];
                float w = beta * beR[r];
                {
                    int tc = t - 8;
                    if (tc < 1) tc = 1;
                    A0[r] = *reinterpret_cast<const float4*>(&ap[(size_t)tc * 64 + st * 8]);
                    A1[r] = *reinterpret_cast<const float4*>(&ap[(size_t)tc * 64 + st * 8 + 4]);
                    beR[r] = be[(size_t)tc * 8 + st];
                }
                beta = fb_matvecT(a0, a1, w);
                if (lane < 8) bwdS[t - 1][lane] = beta;
                if (r == 3 || r == 7) {
                    float s4 = gsum8(beta);
                    beta *= __builtin_amdgcn_rcpf(s4);
                }
            }
        }
#pragma unroll
        for (int r = 0; r < 7; ++r) {
            const int t = 7 - r;
            float4 a0 = A0[r], a1 = A1[r];
            float w = beta * beR[r];
            beta = fb_matvecT(a0, a1, w);
            if (lane < 8) bwdS[t - 1][lane] = beta;
            if (r == 3) {
                float s4 = gsum8(beta);
                beta *= __builtin_amdgcn_rcpf(s4);
            }
        }
    }
    __syncthreads();
    for (int t = tid; t < NT; t += 128) {
        float lg[8], ssum = 0.f;
#pragma unroll
        for (int q = 0; q < 8; ++q) {
            lg[q] = fwdS[t][q] * bwdS[t][q];
            ssum += lg[q];
        }
        float inv = __builtin_amdgcn_rcpf(ssum);
#pragma unroll
        for (int q = 0; q < 8; ++q)
            gamma[((size_t)b * NT + t) * 8 + q] = lg[q] * inv;
    }
}

// ---------------------------------------------------------------------------
// K6: emission via factorized quadratic form.
// red[t] = -0.5*(term1+term0) + xg.(proj-c2x) - 0.5*xg^T G xg + xent
// ---------------------------------------------------------------------------
__global__ __launch_bounds__(256) void k_py(
    const float* __restrict__ x, const float* __restrict__ means,
    const float* __restrict__ gamma, const float* __restrict__ proj,
    const float* __restrict__ term1, const float* __restrict__ Gm,
    const float* __restrict__ c2x, const float* __restrict__ term0,
    const float* __restrict__ xent, float* __restrict__ red)
{
    __shared__ float Gs[32 * 33];
    __shared__ float c2s[32];
    __shared__ float xgS[8][32];
    const int tid = threadIdx.x;
    const int itemBase = blockIdx.x * 8;
    const int b = itemBase >> 10;
    const int t0 = itemBase & (NT - 1);
    for (int i = tid; i < 32 * 33; i += 256) Gs[i] = Gm[i];
    if (tid < 32) c2s[tid] = c2x[tid];
    __syncthreads();
    const int it = tid >> 5;
    const int xo = tid & 31;
    const int t = t0 + it;
    const int item = itemBase + it;
    float xg;
    if (t == 0) {
        xg = x[(size_t)item * 32 + xo];
    } else {
        const float* gp = &gamma[(size_t)item * 8];
        const float* mp = &means[(((size_t)b * 1023 + (t - 1)) * 8) * 32 + xo];
        float4 g0 = *reinterpret_cast<const float4*>(gp);
        float4 g1 = *reinterpret_cast<const float4*>(gp + 4);
        xg = mp[0 * 32] * g0.x;
        xg = fmaf(mp[1 * 32], g0.y, xg);
        xg = fmaf(mp[2 * 32], g0.z, xg);
        xg = fmaf(mp[3 * 32], g0.w, xg);
        xg = fmaf(mp[4 * 32], g1.x, xg);
        xg = fmaf(mp[5 * 32], g1.y, xg);
        xg = fmaf(mp[6 * 32], g1.z, xg);
        xg = fmaf(mp[7 * 32], g1.w, xg);
    }
    xgS[it][xo] = xg;
    __syncthreads();
    float gmv = 0.f;
#pragma unroll 8
    for (int y = 0; y < 32; ++y)
        gmv = fmaf(Gs[xo * 33 + y], xgS[it][y], gmv);
    float val = xg * (proj[(size_t)item * 32 + xo] - c2s[xo] - 0.5f * gmv);
    val += __shfl_xor(val, 1, 64);
    val += __shfl_xor(val, 2, 64);
    val += __shfl_xor(val, 4, 64);
    val += __shfl_xor(val, 8, 64);
    val += __shfl_xor(val, 16, 64);
    if (xo == 0)
        red[item] = -0.5f * (term1[item] + term0[0]) + val + xent[item];
}

__global__ __launch_bounds__(256) void k_final(
    const float* __restrict__ red, const float* __restrict__ log_px,
    float* __restrict__ out)
{
    __shared__ float ssum[4];
    float s = 0.f;
    for (int i = threadIdx.x; i < NB * NT; i += 256) s += red[i];
    if (threadIdx.x < NB) s += log_px[threadIdx.x];
#pragma unroll
    for (int m = 1; m < 64; m <<= 1) s += __shfl_xor(s, m, 64);
    if ((threadIdx.x & 63) == 0) ssum[threadIdx.x >> 6] = s;
    __syncthreads();
    if (threadIdx.x == 0)
        out[0] = (ssum[0] + ssum[1] + ssum[2] + ssum[3]) / (float)NB;
}

// ---------------------------------------------------------------------------
extern "C" void kernel_launch(void* const* d_in, const int* in_sizes, int n_in,
                              void* d_out, int out_size, void* d_ws,
                              size_t ws_size, hipStream_t stream)
{
    const float* ys        = (const float*)d_in[0];
    const float* us        = (const float*)d_in[1];
    const float* eps       = (const float*)d_in[2];
    const float* W1        = (const float*)d_in[3];
    const float* b1        = (const float*)d_in[4];
    const float* Wmu       = (const float*)d_in[5];
    const float* bmu       = (const float*)d_in[6];
    const float* Wlv       = (const float*)d_in[7];
    const float* blv       = (const float*)d_in[8];
    const float* Wz        = (const float*)d_in[9];
    const float* bz        = (const float*)d_in[10];
    const float* A         = (const float*)d_in[11];
    const float* Bu        = (const float*)d_in[12];
    const float* bx        = (const float*)d_in[13];
    const float* x_logvar  = (const float*)d_in[14];
    const float* x0_mean   = (const float*)d_in[15];
    const float* x0_logvar = (const float*)d_in[16];
    const float* C         = (const float*)d_in[17];
    const float* dv        = (const float*)d_in[18];
    const float* y_logvar  = (const float*)d_in[19];
    const float* log_init_z= (const float*)d_in[20];
    float* out = (float*)d_out;

    float* ws = (float*)d_ws;
    float* hbf_f  = ws;                    //  8,388,608 (h bf16)
    float* x      = hbf_f + 8388608;       //  1,048,576
    float* xent   = x + 1048576;           //     32,768
    float* ap1    = xent + 32768;          //  2,097,152
    float* bexp   = ap1 + 2097152;         //    262,144
    float* log_b  = bexp + 262144;         //    262,144
    float* means  = log_b + 262144;        //  8,380,416
    float* gam    = means + 8380416;       //    262,144
    float* log_px = gam + 262144;          //         32
    float* mbsum  = log_px + 32;           //         32
    float* red    = mbsum + 32;            //     32,768
    float* w1t_f  = red + 32768;           //    131,072 (W1^T bf16)
    float* wmlv_f = w1t_f + 131072;        //     16,384 (Wmu|Wlv^T bf16)
    float* proj   = wmlv_f + 16384;        //  1,048,576
    float* term1  = proj + 1048576;        //     32,768
    float* ivbuf  = term1 + 32768;         //        512
    float* w2bf_f = ivbuf + 512;           //      8,192 (W2 bf16)
    float* Gm     = w2bf_f + 8192;         //      1,056
    float* c2x    = Gm + 1056;             //         32
    float* term0  = c2x + 32;              //          1

    unsigned short* hbf  = (unsigned short*)hbf_f;
    unsigned short* w1t  = (unsigned short*)w1t_f;
    unsigned short* wmlv = (unsigned short*)wmlv_f;
    unsigned short* w2bf = (unsigned short*)w2bf_f;

    k_castT    <<<dim3(16, 16), 256, 0, stream>>>(W1, w1t);
    k_cast_mulv<<<dim3(16, 2), 256, 0, stream>>>(Wmu, Wlv, wmlv);
    k_prepc1   <<<1, 256, 0, stream>>>(y_logvar, ivbuf, term0);
    k_prepc2   <<<33, 256, 0, stream>>>(C, dv, ivbuf, w2bf, Gm, c2x);
    k_gemm_h_mfma<<<dim3(4, 256), 256, 0, stream>>>(ys, w1t, b1, hbf);
    k_proj     <<<256, 256, 0, stream>>>(ys, w2bf, dv, ivbuf, proj, term1);
    k_mulv_mfma<<<256, 256, 0, stream>>>(hbf, wmlv, bmu, blv, eps, x, xent);
    k_loga <<<8192, 256, 0, stream>>>(x, Wz, bz, ap1);
    k_means<<<32 * 1023, 256, 0, stream>>>(x, us, A, Bu, bx, x_logvar, means, log_b);
    k_logb0<<<32, 256, 0, stream>>>(x, x0_mean, x0_logvar, log_b);
    k_prep <<<32, 256, 0, stream>>>(log_b, bexp, mbsum);
    k_fb   <<<32, 128, 0, stream>>>(ap1, bexp, mbsum, log_init_z, gam, log_px);
    k_py   <<<4096, 256, 0, stream>>>(x, means, gam, proj, term1, Gm, c2x,
                                      term0, xent, red);
    k_final<<<1, 256, 0, stream>>>(red, log_px, out);
}

// Round 6
// 271.231 us; speedup vs baseline: 4.7828x; 1.1813x over previous
//
#include <hip/hip_runtime.h>
#include <math.h>

#define LOG2PI 1.8378770664093453f

// Problem sizes (fixed)
#define NB 32
#define NT 1024
#define ND 512
#define NH 512
#define NX 32
#define NK 8
#define NU 2

// chunked scan: 1023 transitions = 93 chunks x 11
#define NCH 93
#define CHL 11

typedef __attribute__((ext_vector_type(8))) short bf16x8;
typedef __attribute__((ext_vector_type(4))) float f32x4;

__device__ __forceinline__ unsigned short f2bf(float f) {
    unsigned u = __float_as_uint(f);
    unsigned r = (u + 0x7FFF + ((u >> 16) & 1)) >> 16;
    return (unsigned short)r;
}

// ---------------------------------------------------------------------------
// DPP xor-shuffles within 8-lane groups (VALU pipe, no LDS latency)
// ---------------------------------------------------------------------------
#define DPP_X1 0xB1
#define DPP_X2 0x4E
#define DPP_X3 0x1B
#define DPP_X7 0x141

template <int CTRL>
__device__ __forceinline__ float dppx(float v) {
    return __int_as_float(__builtin_amdgcn_update_dpp(
        0, __float_as_int(v), CTRL, 0xF, 0xF, true));
}

// out_s = sum_e m[s][e] * v_{s^e}  (rows in xor layout, v replicated per 8)
__device__ __forceinline__ float fb_matvec(float4 a0, float4 a1, float v) {
    float p1 = dppx<DPP_X1>(v);
    float p2 = dppx<DPP_X2>(v);
    float p3 = dppx<DPP_X3>(v);
    float p7 = dppx<DPP_X7>(v);
    float p4 = dppx<DPP_X7>(p3);
    float p5 = dppx<DPP_X7>(p2);
    float p6 = dppx<DPP_X7>(p1);
    float c0 = fmaf(a0.y, p1, a0.x * v);
    float c1 = fmaf(a0.w, p3, a0.z * p2);
    float c2 = fmaf(a1.y, p5, a1.x * p4);
    float c3 = fmaf(a1.w, p7, a1.z * p6);
    return (c0 + c1) + (c2 + c3);
}

// out_k = sum_j M[j][k] w_j using the SAME xor-layout rows
__device__ __forceinline__ float fb_matvecT(float4 a0, float4 a1, float w) {
    float q0 = a0.x * w;
    float t1 = dppx<DPP_X1>(a0.y * w);
    float t2 = dppx<DPP_X2>(a0.z * w);
    float t3 = dppx<DPP_X3>(a0.w * w);
    float t7 = dppx<DPP_X7>(a1.w * w);
    float t4 = dppx<DPP_X7>(dppx<DPP_X3>(a1.x * w));
    float t5 = dppx<DPP_X7>(dppx<DPP_X2>(a1.y * w));
    float t6 = dppx<DPP_X7>(dppx<DPP_X1>(a1.z * w));
    return ((q0 + t1) + (t2 + t3)) + ((t4 + t5) + (t6 + t7));
}

// sum over the 8-lane group (replicated result)
__device__ __forceinline__ float gsum8(float v) {
    float s = v + dppx<DPP_X1>(v);
    s = s + dppx<DPP_X2>(s);
    s = s + dppx<DPP_X7>(dppx<DPP_X3>(s));
    return s;
}

__device__ __forceinline__ float lse8_high(float v) {
    float m = v;
    m = fmaxf(m, __shfl_xor(m, 8, 64));
    m = fmaxf(m, __shfl_xor(m, 16, 64));
    m = fmaxf(m, __shfl_xor(m, 32, 64));
    float s = expf(v - m);
    s += __shfl_xor(s, 8, 64);
    s += __shfl_xor(s, 16, 64);
    s += __shfl_xor(s, 32, 64);
    return m + logf(s);
}

// ---------------------------------------------------------------------------
// W1 [K=512][N=512] f32 -> W1T [N][K] bf16
// ---------------------------------------------------------------------------
__global__ __launch_bounds__(256) void k_castT(
    const float* __restrict__ W, unsigned short* __restrict__ WT)
{
    __shared__ float tile[32][33];
    const int bx = blockIdx.x * 32;
    const int by = blockIdx.y * 32;
    const int tx = threadIdx.x & 31, ty = threadIdx.x >> 5;
    for (int i = ty; i < 32; i += 8)
        tile[i][tx] = W[(size_t)(bx + i) * 512 + by + tx];
    __syncthreads();
    for (int i = ty; i < 32; i += 8)
        WT[(size_t)(by + i) * 512 + bx + tx] = f2bf(tile[tx][i]);
}

// Wmu/Wlv [512][32] f32 -> out [64][512] bf16
__global__ __launch_bounds__(256) void k_cast_mulv(
    const float* __restrict__ Wmu, const float* __restrict__ Wlv,
    unsigned short* __restrict__ out)
{
    __shared__ float tile[32][33];
    const float* W = blockIdx.y ? Wlv : Wmu;
    const int base = blockIdx.y * 32;
    const int g = blockIdx.x;
    const int tx = threadIdx.x & 31, ty = threadIdx.x >> 5;
    for (int i = ty; i < 32; i += 8)
        tile[i][tx] = W[(size_t)(g * 32 + i) * 32 + tx];
    __syncthreads();
    for (int i = ty; i < 32; i += 8)
        out[(size_t)(base + i) * 512 + g * 32 + tx] = f2bf(tile[tx][i]);
}

// ---------------------------------------------------------------------------
// prep for emission factorization: ivbuf = exp(-ylv), term0 = sum(ylv+LOG2PI)
// ---------------------------------------------------------------------------
__global__ __launch_bounds__(256) void k_prepc1(
    const float* __restrict__ ylv, float* __restrict__ ivbuf,
    float* __restrict__ term0)
{
    __shared__ float part[256];
    const int tid = threadIdx.x;
    float s = 0.f;
    for (int i = tid; i < 512; i += 256) {
        float lv = ylv[i];
        ivbuf[i] = expf(-lv);
        s += lv + LOG2PI;
    }
    part[tid] = s;
    __syncthreads();
    for (int st = 128; st; st >>= 1) {
        if (tid < st) part[tid] += part[tid + st];
        __syncthreads();
    }
    if (tid == 0) term0[0] = part[0];
}

// blocks 0-31: G[x][y] = sum_d C[x,d]*iv_d*C[y,d] (pad 33) + c2x[x]
// block 32: W2bf[x][d] = bf16(iv_d * C[x,d])
__global__ __launch_bounds__(256) void k_prepc2(
    const float* __restrict__ C, const float* __restrict__ dvec,
    const float* __restrict__ ivbuf, unsigned short* __restrict__ W2bf,
    float* __restrict__ G, float* __restrict__ c2x)
{
    const int x = blockIdx.x;
    const int tid = threadIdx.x;
    if (x == 32) {
        for (int i = tid; i < 32 * 512; i += 256)
            W2bf[i] = f2bf(C[i] * ivbuf[i & 511]);
        return;
    }
    const int y = tid >> 3, seg = tid & 7;
    const float* Cx = &C[(size_t)x * 512];
    const float* Cy = &C[(size_t)y * 512];
    float p = 0.f;
    for (int j = 0; j < 64; ++j) {
        int dcol = seg * 64 + j;
        p = fmaf(Cx[dcol] * ivbuf[dcol], Cy[dcol], p);
    }
    p = gsum8(p);
    if (seg == 0) G[x * 33 + y] = p;
    if (tid < 8) {
        float q = 0.f;
        for (int j = 0; j < 64; ++j) {
            int dcol = tid * 64 + j;
            q = fmaf(Cx[dcol] * ivbuf[dcol], dvec[dcol], q);
        }
        q = gsum8(q);
        if (tid == 0) c2x[x] = q;
    }
}

// ---------------------------------------------------------------------------
// K1: h_bf = bf16(tanh(ys @ W1 + b1)). Reads f32 ys, casts in-register.
// ---------------------------------------------------------------------------
__global__ __launch_bounds__(256) void k_gemm_h_mfma(
    const float* __restrict__ ys,
    const unsigned short* __restrict__ Bbf,
    const float* __restrict__ b1, unsigned short* __restrict__ hb)
{
    __shared__ unsigned short As[128 * 64];
    __shared__ unsigned short Bs[128 * 64];
    const int tid = threadIdx.x;
    const int bm = blockIdx.y * 128;
    const int bn = blockIdx.x * 128;
    const int wid = tid >> 6, lane = tid & 63;
    const int wm = wid >> 1, wn = wid & 1;

    f32x4 acc[4][4];
#pragma unroll
    for (int m = 0; m < 4; ++m)
#pragma unroll
        for (int n = 0; n < 4; ++n)
            acc[m][n] = (f32x4){0.f, 0.f, 0.f, 0.f};

    for (int k0 = 0; k0 < 512; k0 += 64) {
#pragma unroll
        for (int r = 0; r < 4; ++r) {
            int l = tid + r * 256;
            int row = l >> 3, c8 = l & 7;
            int sidx = row * 8 + (c8 ^ (row & 7));
            const float4 f0 = *reinterpret_cast<const float4*>(
                &ys[(size_t)(bm + row) * 512 + k0 + c8 * 8]);
            const float4 f1 = *reinterpret_cast<const float4*>(
                &ys[(size_t)(bm + row) * 512 + k0 + c8 * 8 + 4]);
            uint4 ua;
            ua.x = (unsigned)f2bf(f0.x) | ((unsigned)f2bf(f0.y) << 16);
            ua.y = (unsigned)f2bf(f0.z) | ((unsigned)f2bf(f0.w) << 16);
            ua.z = (unsigned)f2bf(f1.x) | ((unsigned)f2bf(f1.y) << 16);
            ua.w = (unsigned)f2bf(f1.z) | ((unsigned)f2bf(f1.w) << 16);
            *reinterpret_cast<uint4*>(&As[sidx * 8]) = ua;
            uint4 vb = *reinterpret_cast<const uint4*>(
                &Bbf[(size_t)(bn + row) * 512 + k0 + c8 * 8]);
            *reinterpret_cast<uint4*>(&Bs[sidx * 8]) = vb;
        }
        __syncthreads();
#pragma unroll
        for (int kh = 0; kh < 2; ++kh) {
            bf16x8 af[4], bfr[4];
            const int c8r = kh * 4 + (lane >> 4);
#pragma unroll
            for (int m = 0; m < 4; ++m) {
                int rA = wm * 64 + m * 16 + (lane & 15);
                af[m] = *reinterpret_cast<bf16x8*>(
                    &As[rA * 64 + (c8r ^ (rA & 7)) * 8]);
            }
#pragma unroll
            for (int n = 0; n < 4; ++n) {
                int rB = wn * 64 + n * 16 + (lane & 15);
                bfr[n] = *reinterpret_cast<bf16x8*>(
                    &Bs[rB * 64 + (c8r ^ (rB & 7)) * 8]);
            }
#pragma unroll
            for (int m = 0; m < 4; ++m)
#pragma unroll
                for (int n = 0; n < 4; ++n)
                    acc[m][n] = __builtin_amdgcn_mfma_f32_16x16x32_bf16(
                        af[m], bfr[n], acc[m][n], 0, 0, 0);
        }
        __syncthreads();
    }
    float b1v[4];
#pragma unroll
    for (int n = 0; n < 4; ++n)
        b1v[n] = b1[bn + wn * 64 + n * 16 + (lane & 15)];
#pragma unroll
    for (int m = 0; m < 4; ++m) {
#pragma unroll
        for (int q = 0; q < 4; ++q) {
            int row = bm + wm * 64 + m * 16 + (lane >> 4) * 4 + q;
#pragma unroll
            for (int n = 0; n < 4; ++n) {
                int col = bn + wn * 64 + n * 16 + (lane & 15);
                hb[(size_t)row * 512 + col] = f2bf(tanhf(acc[m][n][q] + b1v[n]));
            }
        }
    }
}

// ---------------------------------------------------------------------------
// K2: [mu|lv] = h_bf @ Wt^T via MFMA; epilogue fuses x, xent
// ---------------------------------------------------------------------------
__global__ __launch_bounds__(256) void k_mulv_mfma(
    const unsigned short* __restrict__ hbf,
    const unsigned short* __restrict__ Wt,
    const float* __restrict__ bmu, const float* __restrict__ blv,
    const float* __restrict__ eps,
    float* __restrict__ x, float* __restrict__ xent)
{
    __shared__ unsigned short As[128 * 64];
    __shared__ unsigned short Bs[64 * 64];
    const int tid = threadIdx.x;
    const int bm = blockIdx.x * 128;
    const int wid = tid >> 6, lane = tid & 63;
    f32x4 acc[2][4];
#pragma unroll
    for (int m = 0; m < 2; ++m)
#pragma unroll
        for (int n = 0; n < 4; ++n)
            acc[m][n] = (f32x4){0.f, 0.f, 0.f, 0.f};

    for (int k0 = 0; k0 < 512; k0 += 64) {
#pragma unroll
        for (int r = 0; r < 4; ++r) {
            int l = tid + r * 256, row = l >> 3, c8 = l & 7;
            int sidx = row * 8 + (c8 ^ (row & 7));
            uint4 v = *reinterpret_cast<const uint4*>(
                &hbf[(size_t)(bm + row) * 512 + k0 + c8 * 8]);
            *reinterpret_cast<uint4*>(&As[sidx * 8]) = v;
        }
#pragma unroll
        for (int r = 0; r < 2; ++r) {
            int l = tid + r * 256, row = l >> 3, c8 = l & 7;
            int sidx = row * 8 + (c8 ^ (row & 7));
            uint4 v = *reinterpret_cast<const uint4*>(
                &Wt[(size_t)row * 512 + k0 + c8 * 8]);
            *reinterpret_cast<uint4*>(&Bs[sidx * 8]) = v;
        }
        __syncthreads();
#pragma unroll
        for (int kh = 0; kh < 2; ++kh) {
            const int c8r = kh * 4 + (lane >> 4);
            bf16x8 af[2], bfr[4];
#pragma unroll
            for (int m = 0; m < 2; ++m) {
                int rA = wid * 32 + m * 16 + (lane & 15);
                af[m] = *reinterpret_cast<bf16x8*>(
                    &As[rA * 64 + (c8r ^ (rA & 7)) * 8]);
            }
#pragma unroll
            for (int n = 0; n < 4; ++n) {
                int rB = n * 16 + (lane & 15);
                bfr[n] = *reinterpret_cast<bf16x8*>(
                    &Bs[rB * 64 + (c8r ^ (rB & 7)) * 8]);
            }
#pragma unroll
            for (int m = 0; m < 2; ++m)
#pragma unroll
                for (int n = 0; n < 4; ++n)
                    acc[m][n] = __builtin_amdgcn_mfma_f32_16x16x32_bf16(
                        af[m], bfr[n], acc[m][n], 0, 0, 0);
        }
        __syncthreads();
    }
    const int o0 = lane & 15, o1 = 16 + (lane & 15);
    const float bm0 = bmu[o0], bm1 = bmu[o1];
    const float bl0 = blv[o0], bl1 = blv[o1];
#pragma unroll
    for (int m = 0; m < 2; ++m) {
#pragma unroll
        for (int q = 0; q < 4; ++q) {
            int row = bm + wid * 32 + m * 16 + (lane >> 4) * 4 + q;
            float mu0 = acc[m][0][q] + bm0;
            float mu1 = acc[m][1][q] + bm1;
            float lv0 = acc[m][2][q] + bl0;
            float lv1 = acc[m][3][q] + bl1;
            float e0 = eps[(size_t)row * 32 + o0];
            float e1 = eps[(size_t)row * 32 + o1];
            x[(size_t)row * 32 + o0] = mu0 + expf(0.5f * lv0) * e0;
            x[(size_t)row * 32 + o1] = mu1 + expf(0.5f * lv1) * e1;
            float pe = (e0 * e0 + lv0) + (e1 * e1 + lv1);
            pe += __shfl_xor(pe, 1, 64);
            pe += __shfl_xor(pe, 2, 64);
            pe += __shfl_xor(pe, 4, 64);
            pe += __shfl_xor(pe, 8, 64);
            if ((lane & 15) == 0)
                xent[row] = 0.5f * (pe + 32.f * LOG2PI);
        }
    }
}

// ---------------------------------------------------------------------------
// K2b: proj = ys @ W2bf^T (M=32768, N=32, K=512) + term1 from f32 ys.
// ---------------------------------------------------------------------------
__global__ __launch_bounds__(256) void k_proj(
    const float* __restrict__ ys, const unsigned short* __restrict__ W2bf,
    const float* __restrict__ dvec, const float* __restrict__ ivbuf,
    float* __restrict__ proj, float* __restrict__ term1)
{
    __shared__ unsigned short As[128 * 64];
    __shared__ unsigned short Bs[32 * 64];
    const int tid = threadIdx.x;
    const int bm = blockIdx.x * 128;
    const int wid = tid >> 6, lane = tid & 63;
    const int c8 = tid & 7;
    f32x4 acc[2][2];
#pragma unroll
    for (int m = 0; m < 2; ++m)
#pragma unroll
        for (int n = 0; n < 2; ++n)
            acc[m][n] = (f32x4){0.f, 0.f, 0.f, 0.f};
    float t1p[4] = {0.f, 0.f, 0.f, 0.f};

    for (int k0 = 0; k0 < 512; k0 += 64) {
        const float4 dv0 = *reinterpret_cast<const float4*>(&dvec[k0 + c8 * 8]);
        const float4 dv1 = *reinterpret_cast<const float4*>(&dvec[k0 + c8 * 8 + 4]);
        const float4 iv0 = *reinterpret_cast<const float4*>(&ivbuf[k0 + c8 * 8]);
        const float4 iv1 = *reinterpret_cast<const float4*>(&ivbuf[k0 + c8 * 8 + 4]);
#pragma unroll
        for (int r = 0; r < 4; ++r) {
            int l = tid + r * 256;
            int row = l >> 3;
            int sidx = row * 8 + (c8 ^ (row & 7));
            const float4 f0 = *reinterpret_cast<const float4*>(
                &ys[(size_t)(bm + row) * 512 + k0 + c8 * 8]);
            const float4 f1 = *reinterpret_cast<const float4*>(
                &ys[(size_t)(bm + row) * 512 + k0 + c8 * 8 + 4]);
            float g0 = f0.x - dv0.x, g1 = f0.y - dv0.y;
            float g2 = f0.z - dv0.z, g3 = f0.w - dv0.w;
            float g4 = f1.x - dv1.x, g5 = f1.y - dv1.y;
            float g6 = f1.z - dv1.z, g7 = f1.w - dv1.w;
            t1p[r] += (g0 * g0 * iv0.x + g1 * g1 * iv0.y)
                    + (g2 * g2 * iv0.z + g3 * g3 * iv0.w)
                    + (g4 * g4 * iv1.x + g5 * g5 * iv1.y)
                    + (g6 * g6 * iv1.z + g7 * g7 * iv1.w);
            uint4 ua;
            ua.x = (unsigned)f2bf(f0.x) | ((unsigned)f2bf(f0.y) << 16);
            ua.y = (unsigned)f2bf(f0.z) | ((unsigned)f2bf(f0.w) << 16);
            ua.z = (unsigned)f2bf(f1.x) | ((unsigned)f2bf(f1.y) << 16);
            ua.w = (unsigned)f2bf(f1.z) | ((unsigned)f2bf(f1.w) << 16);
            *reinterpret_cast<uint4*>(&As[sidx * 8]) = ua;
        }
        {
            int row = tid >> 3;
            int sidx = row * 8 + (c8 ^ (row & 7));
            uint4 v = *reinterpret_cast<const uint4*>(
                &W2bf[(size_t)row * 512 + k0 + c8 * 8]);
            *reinterpret_cast<uint4*>(&Bs[sidx * 8]) = v;
        }
        __syncthreads();
#pragma unroll
        for (int kh = 0; kh < 2; ++kh) {
            const int c8r = kh * 4 + (lane >> 4);
            bf16x8 af[2], bfr[2];
#pragma unroll
            for (int m = 0; m < 2; ++m) {
                int rA = wid * 32 + m * 16 + (lane & 15);
                af[m] = *reinterpret_cast<bf16x8*>(
                    &As[rA * 64 + (c8r ^ (rA & 7)) * 8]);
            }
#pragma unroll
            for (int n = 0; n < 2; ++n) {
                int rB = n * 16 + (lane & 15);
                bfr[n] = *reinterpret_cast<bf16x8*>(
                    &Bs[rB * 64 + (c8r ^ (rB & 7)) * 8]);
            }
#pragma unroll
            for (int m = 0; m < 2; ++m)
#pragma unroll
                for (int n = 0; n < 2; ++n)
                    acc[m][n] = __builtin_amdgcn_mfma_f32_16x16x32_bf16(
                        af[m], bfr[n], acc[m][n], 0, 0, 0);
        }
        __syncthreads();
    }
#pragma unroll
    for (int m = 0; m < 2; ++m)
#pragma unroll
        for (int q = 0; q < 4; ++q) {
            int row = bm + wid * 32 + m * 16 + (lane >> 4) * 4 + q;
#pragma unroll
            for (int n = 0; n < 2; ++n) {
                int col = n * 16 + (lane & 15);
                proj[(size_t)row * 32 + col] = acc[m][n][q];
            }
        }
#pragma unroll
    for (int r = 0; r < 4; ++r) {
        float s = gsum8(t1p[r]);
        if ((tid & 7) == 0) term1[bm + (tid >> 3) + r * 32] = s;
    }
}

// ---------------------------------------------------------------------------
// K3: softmax_j(x[b,t-1] @ Wz + bz) -> ap1[t][s][e] = a[s][s^e]
// ---------------------------------------------------------------------------
__global__ __launch_bounds__(256) void k_loga(
    const float* __restrict__ x, const float* __restrict__ Wz,
    const float* __restrict__ bz, float* __restrict__ ap1)
{
    const int tid = threadIdx.x;
    const int item = blockIdx.x * 4 + (tid >> 6);
    const int lane = tid & 63;
    const int t = item & (NT - 1);
    if (t == 0) return;
    const int j = lane >> 3, k = lane & 7;
    const float* xr = &x[((size_t)item - 1) * 32];
    float acc = bz[lane];
#pragma unroll
    for (int e = 0; e < 32; ++e) acc = fmaf(xr[e], Wz[e * 64 + lane], acc);
    float lse = lse8_high(acc);
    ap1[(size_t)item * 64 + j * 8 + (j ^ k)] = expf(acc - lse);
}

// ---------------------------------------------------------------------------
// K4: means + log_b
// ---------------------------------------------------------------------------
__global__ __launch_bounds__(256) void k_means(
    const float* __restrict__ x, const float* __restrict__ us,
    const float* __restrict__ A, const float* __restrict__ Bu,
    const float* __restrict__ bx, const float* __restrict__ x_logvar,
    float* __restrict__ means, float* __restrict__ log_b)
{
    __shared__ float xs[32];
    __shared__ float uu[2];
    const int item = blockIdx.x;
    const int b = item / 1023;
    const int tm = item - b * 1023;
    const int tid = threadIdx.x;
    const int k = tid >> 5, xo = tid & 31;
    if (tid < 32) xs[tid] = x[((size_t)b * NT + tm) * 32 + tid];
    if (tid < 2) uu[tid] = us[((size_t)b * NT + tm + 1) * 2 + tid];
    __syncthreads();
    float acc = bx[k * 32 + xo];
#pragma unroll
    for (int e = 0; e < 32; ++e)
        acc = fmaf(xs[e], A[((size_t)k * 32 + e) * 32 + xo], acc);
    acc = fmaf(uu[0], Bu[((size_t)k * 2 + 0) * 32 + xo], acc);
    acc = fmaf(uu[1], Bu[((size_t)k * 2 + 1) * 32 + xo], acc);
    means[((size_t)item * 8 + k) * 32 + xo] = acc;
    float xv = x[((size_t)b * NT + tm + 1) * 32 + xo];
    float lvv = x_logvar[k * 32 + xo];
    float dd = xv - acc;
    float term = -0.5f * (dd * dd * expf(-lvv) + lvv + LOG2PI);
    for (int m = 16; m; m >>= 1) term += __shfl_down(term, m, 32);
    if (xo == 0) log_b[((size_t)b * NT + tm + 1) * 8 + k] = term;
}

__global__ __launch_bounds__(256) void k_logb0(
    const float* __restrict__ x, const float* __restrict__ x0_mean,
    const float* __restrict__ x0_logvar, float* __restrict__ log_b)
{
    const int b = blockIdx.x;
    const int tid = threadIdx.x;
    const int k = tid >> 5, xo = tid & 31;
    float xv = x[((size_t)b * NT) * 32 + xo];
    float mm = x0_mean[k * 32 + xo];
    float lvv = x0_logvar[k * 32 + xo];
    float dd = xv - mm;
    float term = -0.5f * (dd * dd * expf(-lvv) + lvv + LOG2PI);
    for (int m = 16; m; m >>= 1) term += __shfl_down(term, m, 32);
    if (xo == 0) log_b[(size_t)b * NT * 8 + k] = term;
}

// ---------------------------------------------------------------------------
// K4c: bexp/mbsum prep for the scan
// ---------------------------------------------------------------------------
__global__ __launch_bounds__(256) void k_prep(
    const float* __restrict__ log_b, float* __restrict__ bexp,
    float* __restrict__ mbsum)
{
    __shared__ float part[256];
    const int b = blockIdx.x;
    const int tid = threadIdx.x;
    float msum = 0.f;
    for (int t = tid; t < NT; t += 256) {
        const float* lbp = &log_b[((size_t)b * NT + t) * 8];
        float4 l0 = *reinterpret_cast<const float4*>(lbp);
        float4 l1 = *reinterpret_cast<const float4*>(lbp + 4);
        float mm = fmaxf(fmaxf(fmaxf(l0.x, l0.y), fmaxf(l0.z, l0.w)),
                         fmaxf(fmaxf(l1.x, l1.y), fmaxf(l1.z, l1.w)));
        float4 e0, e1;
        e0.x = expf(l0.x - mm); e0.y = expf(l0.y - mm);
        e0.z = expf(l0.z - mm); e0.w = expf(l0.w - mm);
        e1.x = expf(l1.x - mm); e1.y = expf(l1.y - mm);
        e1.z = expf(l1.z - mm); e1.w = expf(l1.w - mm);
        float* bp = &bexp[((size_t)b * NT + t) * 8];
        *reinterpret_cast<float4*>(bp) = e0;
        *reinterpret_cast<float4*>(bp + 4) = e1;
        msum += mm;
    }
    part[tid] = msum;
    __syncthreads();
    for (int s = 128; s; s >>= 1) {
        if (tid < s) part[tid] += part[tid + s];
        __syncthreads();
    }
    if (tid == 0) mbsum[b] = part[0];
}

// ---------------------------------------------------------------------------
// K5a: chunk products. One 64-lane wave per (b,chunk); lane = j*8+k holds
// running product element P[j][k]; P <- T_t P via 7 shfl_xor partners.
// Output in xor layout Pfx[b][c][s][e] = P[s][s^e], plus log-scale sA.
// ---------------------------------------------------------------------------
__global__ __launch_bounds__(256) void k_fbA(
    const float* __restrict__ ap1, const float* __restrict__ bexp,
    float* __restrict__ Pfx, float* __restrict__ sA)
{
    const int tid = threadIdx.x;
    const int wg = blockIdx.x * 4 + (tid >> 6);   // 0..2975
    const int lane = tid & 63;
    const int b = wg / NCH;
    const int c = wg - b * NCH;                    // 0..92 (chunk c+1)
    const int j = lane >> 3, k = lane & 7;
    const float* ap = &ap1[(size_t)b * NT * 64];
    const float* be = &bexp[(size_t)b * NT * 8];
    int t = CHL * c + 1;
    float P = be[t * 8 + j] * ap[t * 64 + j * 8 + (j ^ k)];
    float sacc = 0.f;
    for (int i = 1; i < CHL; ++i) {
        ++t;
        float4 m0 = *reinterpret_cast<const float4*>(&ap[(size_t)t * 64 + j * 8]);
        float4 m1 = *reinterpret_cast<const float4*>(&ap[(size_t)t * 64 + j * 8 + 4]);
        float bj = be[(size_t)t * 8 + j];
        float x1 = __shfl_xor(P, 8, 64);
        float x2 = __shfl_xor(P, 16, 64);
        float x3 = __shfl_xor(P, 24, 64);
        float x4 = __shfl_xor(P, 32, 64);
        float x5 = __shfl_xor(P, 40, 64);
        float x6 = __shfl_xor(P, 48, 64);
        float x7 = __shfl_xor(P, 56, 64);
        float c0 = fmaf(m0.y, x1, m0.x * P);
        float c1 = fmaf(m0.w, x3, m0.z * x2);
        float c2 = fmaf(m1.y, x5, m1.x * x4);
        float c3 = fmaf(m1.w, x7, m1.z * x6);
        P = bj * ((c0 + c1) + (c2 + c3));
        if ((i & 3) == 3) {  // renorm (log applied scale)
            float mx = P;
            mx = fmaxf(mx, __shfl_xor(mx, 1, 64));
            mx = fmaxf(mx, __shfl_xor(mx, 2, 64));
            mx = fmaxf(mx, __shfl_xor(mx, 4, 64));
            mx = fmaxf(mx, __shfl_xor(mx, 8, 64));
            mx = fmaxf(mx, __shfl_xor(mx, 16, 64));
            mx = fmaxf(mx, __shfl_xor(mx, 32, 64));
            mx = fmaxf(mx, 1e-30f);
            float r = __builtin_amdgcn_rcpf(mx);
            P *= r;
            sacc -= __logf(r);
        }
    }
    Pfx[((size_t)b * NCH + c) * 64 + j * 8 + (j ^ k)] = P;
    if (lane == 0) sA[b * NCH + c] = sacc;
}

// ---------------------------------------------------------------------------
// K5b: boundary scans over chunk matrices (93 serial steps).
// Block = 2 waves: wave0 fwd (alphaB + log_px), wave1 bwd (betaB).
// ---------------------------------------------------------------------------
__global__ __launch_bounds__(128) void k_fbB(
    const float* __restrict__ Pfx, const float* __restrict__ sA,
    const float* __restrict__ bexp, const float* __restrict__ mbsum,
    const float* __restrict__ log_init_z,
    float* __restrict__ alphaB, float* __restrict__ betaB,
    float* __restrict__ log_px)
{
    const int b = blockIdx.x;
    const int tid = threadIdx.x;
    const int wave = tid >> 6;
    const int lane = tid & 63;
    const int st = lane & 7;
    const float* pf = &Pfx[(size_t)b * NCH * 64];
    if (wave == 0) {
        float liv[8];
        float mz = -1e30f, sz = 0.f;
#pragma unroll
        for (int q = 0; q < 8; ++q) liv[q] = log_init_z[q];
#pragma unroll
        for (int q = 0; q < 8; ++q) mz = fmaxf(mz, liv[q]);
#pragma unroll
        for (int q = 0; q < 8; ++q) sz += expf(liv[q] - mz);
        float alpha = (expf(liv[st] - mz) / sz) * bexp[(size_t)b * NT * 8 + st];
        float logS = 0.f, sAsum = 0.f;
        {
            float s = fmaxf(gsum8(alpha), 1e-35f);
            logS += __logf(s);
            alpha *= __builtin_amdgcn_rcpf(s);
        }
        if (lane < 8) alphaB[((size_t)b * (NCH + 1)) * 8 + lane] = alpha;
        for (int c = 0; c < NCH; ++c) {
            float4 a0 = *reinterpret_cast<const float4*>(&pf[(size_t)c * 64 + st * 8]);
            float4 a1 = *reinterpret_cast<const float4*>(&pf[(size_t)c * 64 + st * 8 + 4]);
            alpha = fb_matvec(a0, a1, alpha);
            float s = fmaxf(gsum8(alpha), 1e-35f);
            logS += __logf(s);
            alpha *= __builtin_amdgcn_rcpf(s);
            sAsum += sA[b * NCH + c];
            if (lane < 8) alphaB[((size_t)b * (NCH + 1) + c + 1) * 8 + lane] = alpha;
        }
        if (lane == 0) log_px[b] = mbsum[b] + sAsum + logS;
    } else {
        float beta = 1.f;
        if (lane < 8) betaB[((size_t)b * (NCH + 1) + NCH) * 8 + lane] = 1.f;
        for (int c = NCH - 1; c >= 0; --c) {
            float4 a0 = *reinterpret_cast<const float4*>(&pf[(size_t)c * 64 + st * 8]);
            float4 a1 = *reinterpret_cast<const float4*>(&pf[(size_t)c * 64 + st * 8 + 4]);
            beta = fb_matvecT(a0, a1, beta);
            float s = fmaxf(gsum8(beta), 1e-35f);
            beta *= __builtin_amdgcn_rcpf(s);
            if (lane < 8) betaB[((size_t)b * (NCH + 1) + c) * 8 + lane] = beta;
        }
    }
}

// ---------------------------------------------------------------------------
// K5c: within-chunk recompute + gamma. 8-lane group per (b,chunk): fwd pass
// stores alphas in LDS, bwd pass fuses gamma write.
// ---------------------------------------------------------------------------
__global__ __launch_bounds__(256) void k_fbC(
    const float* __restrict__ ap1, const float* __restrict__ bexp,
    const float* __restrict__ alphaB, const float* __restrict__ betaB,
    float* __restrict__ gamma)
{
    __shared__ float alphaS[32][CHL][8];
    const int tid = threadIdx.x;
    const int g = tid >> 3;
    const int st = tid & 7;
    const int task = blockIdx.x * 32 + g;   // 0..2975
    const int b = task / NCH;
    const int c = task - b * NCH;           // 0..92
    const float* ap = &ap1[(size_t)b * NT * 64];
    const float* be = &bexp[(size_t)b * NT * 8];
    const int t0 = CHL * c;
    // fwd
    float alpha = alphaB[((size_t)b * (NCH + 1) + c) * 8 + st];
#pragma unroll
    for (int i = 1; i <= CHL; ++i) {
        int t = t0 + i;
        float4 a0 = *reinterpret_cast<const float4*>(&ap[(size_t)t * 64 + st * 8]);
        float4 a1 = *reinterpret_cast<const float4*>(&ap[(size_t)t * 64 + st * 8 + 4]);
        float bv = be[(size_t)t * 8 + st];
        alpha = fb_matvec(a0, a1, alpha) * bv;
        if (i == 5)
            alpha *= __builtin_amdgcn_rcpf(fmaxf(gsum8(alpha), 1e-35f));
        alphaS[g][i - 1][st] = alpha;
    }
    // bwd + gamma
    float beta = betaB[((size_t)b * (NCH + 1) + c + 1) * 8 + st];
#pragma unroll
    for (int i = CHL; i >= 1; --i) {
        int t = t0 + i;
        float gv = alphaS[g][i - 1][st] * beta;
        float s = fmaxf(gsum8(gv), 1e-35f);
        gamma[((size_t)b * NT + t) * 8 + st] = gv * __builtin_amdgcn_rcpf(s);
        float4 a0 = *reinterpret_cast<const float4*>(&ap[(size_t)t * 64 + st * 8]);
        float4 a1 = *reinterpret_cast<const float4*>(&ap[(size_t)t * 64 + st * 8 + 4]);
        float bv = be[(size_t)t * 8 + st];
        beta = fb_matvecT(a0, a1, beta * bv);
        if (i == 6)
            beta *= __builtin_amdgcn_rcpf(fmaxf(gsum8(beta), 1e-35f));
    }
    if (c == 0) {
        float a0v = alphaB[((size_t)b * (NCH + 1)) * 8 + st];
        float gv = a0v * beta;
        float s = fmaxf(gsum8(gv), 1e-35f);
        gamma[((size_t)b * NT) * 8 + st] = gv * __builtin_amdgcn_rcpf(s);
    }
}

// ---------------------------------------------------------------------------
// K6: emission via factorized quadratic form.
// ---------------------------------------------------------------------------
__global__ __launch_bounds__(256) void k_py(
    const float* __restrict__ x, const float* __restrict__ means,
    const float* __restrict__ gamma, const float* __restrict__ proj,
    const float* __restrict__ term1, const float* __restrict__ Gm,
    const float* __restrict__ c2x, const float* __restrict__ term0,
    const float* __restrict__ xent, float* __restrict__ red)
{
    __shared__ float Gs[32 * 33];
    __shared__ float c2s[32];
    __shared__ float xgS[8][32];
    const int tid = threadIdx.x;
    const int itemBase = blockIdx.x * 8;
    const int b = itemBase >> 10;
    const int t0 = itemBase & (NT - 1);
    for (int i = tid; i < 32 * 33; i += 256) Gs[i] = Gm[i];
    if (tid < 32) c2s[tid] = c2x[tid];
    __syncthreads();
    const int it = tid >> 5;
    const int xo = tid & 31;
    const int t = t0 + it;
    const int item = itemBase + it;
    float xg;
    if (t == 0) {
        xg = x[(size_t)item * 32 + xo];
    } else {
        const float* gp = &gamma[(size_t)item * 8];
        const float* mp = &means[(((size_t)b * 1023 + (t - 1)) * 8) * 32 + xo];
        float4 g0 = *reinterpret_cast<const float4*>(gp);
        float4 g1 = *reinterpret_cast<const float4*>(gp + 4);
        xg = mp[0 * 32] * g0.x;
        xg = fmaf(mp[1 * 32], g0.y, xg);
        xg = fmaf(mp[2 * 32], g0.z, xg);
        xg = fmaf(mp[3 * 32], g0.w, xg);
        xg = fmaf(mp[4 * 32], g1.x, xg);
        xg = fmaf(mp[5 * 32], g1.y, xg);
        xg = fmaf(mp[6 * 32], g1.z, xg);
        xg = fmaf(mp[7 * 32], g1.w, xg);
    }
    xgS[it][xo] = xg;
    __syncthreads();
    float gmv = 0.f;
#pragma unroll 8
    for (int y = 0; y < 32; ++y)
        gmv = fmaf(Gs[xo * 33 + y], xgS[it][y], gmv);
    float val = xg * (proj[(size_t)item * 32 + xo] - c2s[xo] - 0.5f * gmv);
    val += __shfl_xor(val, 1, 64);
    val += __shfl_xor(val, 2, 64);
    val += __shfl_xor(val, 4, 64);
    val += __shfl_xor(val, 8, 64);
    val += __shfl_xor(val, 16, 64);
    if (xo == 0)
        red[item] = -0.5f * (term1[item] + term0[0]) + val + xent[item];
}

__global__ __launch_bounds__(256) void k_final(
    const float* __restrict__ red, const float* __restrict__ log_px,
    float* __restrict__ out)
{
    __shared__ float ssum[4];
    float s = 0.f;
    for (int i = threadIdx.x; i < NB * NT; i += 256) s += red[i];
    if (threadIdx.x < NB) s += log_px[threadIdx.x];
#pragma unroll
    for (int m = 1; m < 64; m <<= 1) s += __shfl_xor(s, m, 64);
    if ((threadIdx.x & 63) == 0) ssum[threadIdx.x >> 6] = s;
    __syncthreads();
    if (threadIdx.x == 0)
        out[0] = (ssum[0] + ssum[1] + ssum[2] + ssum[3]) / (float)NB;
}

// ---------------------------------------------------------------------------
extern "C" void kernel_launch(void* const* d_in, const int* in_sizes, int n_in,
                              void* d_out, int out_size, void* d_ws,
                              size_t ws_size, hipStream_t stream)
{
    const float* ys        = (const float*)d_in[0];
    const float* us        = (const float*)d_in[1];
    const float* eps       = (const float*)d_in[2];
    const float* W1        = (const float*)d_in[3];
    const float* b1        = (const float*)d_in[4];
    const float* Wmu       = (const float*)d_in[5];
    const float* bmu       = (const float*)d_in[6];
    const float* Wlv       = (const float*)d_in[7];
    const float* blv       = (const float*)d_in[8];
    const float* Wz        = (const float*)d_in[9];
    const float* bz        = (const float*)d_in[10];
    const float* A         = (const float*)d_in[11];
    const float* Bu        = (const float*)d_in[12];
    const float* bx        = (const float*)d_in[13];
    const float* x_logvar  = (const float*)d_in[14];
    const float* x0_mean   = (const float*)d_in[15];
    const float* x0_logvar = (const float*)d_in[16];
    const float* C         = (const float*)d_in[17];
    const float* dv        = (const float*)d_in[18];
    const float* y_logvar  = (const float*)d_in[19];
    const float* log_init_z= (const float*)d_in[20];
    float* out = (float*)d_out;

    float* ws = (float*)d_ws;
    float* hbf_f  = ws;                    //  8,388,608 (h bf16)
    float* x      = hbf_f + 8388608;       //  1,048,576
    float* xent   = x + 1048576;           //     32,768
    float* ap1    = xent + 32768;          //  2,097,152
    float* bexp   = ap1 + 2097152;         //    262,144
    float* log_b  = bexp + 262144;         //    262,144
    float* means  = log_b + 262144;        //  8,380,416
    float* gam    = means + 8380416;       //    262,144
    float* log_px = gam + 262144;          //         32
    float* mbsum  = log_px + 32;           //         32
    float* red    = mbsum + 32;            //     32,768
    float* w1t_f  = red + 32768;           //    131,072 (W1^T bf16)
    float* wmlv_f = w1t_f + 131072;        //     16,384 (Wmu|Wlv^T bf16)
    float* proj   = wmlv_f + 16384;        //  1,048,576
    float* term1  = proj + 1048576;        //     32,768
    float* ivbuf  = term1 + 32768;         //        512
    float* w2bf_f = ivbuf + 512;           //      8,192 (W2 bf16)
    float* Gm     = w2bf_f + 8192;         //      1,056
    float* c2x    = Gm + 1056;             //         32
    float* term0  = c2x + 32;              //          1
    float* Pfx    = term0 + 1;             //    190,464 (32*93*64)
    float* sA     = Pfx + 190464;          //      2,976
    float* alphaB = sA + 2976;             //     24,064 (32*94*8)
    float* betaB  = alphaB + 24064;        //     24,064

    unsigned short* hbf  = (unsigned short*)hbf_f;
    unsigned short* w1t  = (unsigned short*)w1t_f;
    unsigned short* wmlv = (unsigned short*)wmlv_f;
    unsigned short* w2bf = (unsigned short*)w2bf_f;

    k_castT    <<<dim3(16, 16), 256, 0, stream>>>(W1, w1t);
    k_cast_mulv<<<dim3(16, 2), 256, 0, stream>>>(Wmu, Wlv, wmlv);
    k_prepc1   <<<1, 256, 0, stream>>>(y_logvar, ivbuf, term0);
    k_prepc2   <<<33, 256, 0, stream>>>(C, dv, ivbuf, w2bf, Gm, c2x);
    k_gemm_h_mfma<<<dim3(4, 256), 256, 0, stream>>>(ys, w1t, b1, hbf);
    k_proj     <<<256, 256, 0, stream>>>(ys, w2bf, dv, ivbuf, proj, term1);
    k_mulv_mfma<<<256, 256, 0, stream>>>(hbf, wmlv, bmu, blv, eps, x, xent);
    k_loga <<<8192, 256, 0, stream>>>(x, Wz, bz, ap1);
    k_means<<<32 * 1023, 256, 0, stream>>>(x, us, A, Bu, bx, x_logvar, means, log_b);
    k_logb0<<<32, 256, 0, stream>>>(x, x0_mean, x0_logvar, log_b);
    k_prep <<<32, 256, 0, stream>>>(log_b, bexp, mbsum);
    k_fbA  <<<744, 256, 0, stream>>>(ap1, bexp, Pfx, sA);
    k_fbB  <<<32, 128, 0, stream>>>(Pfx, sA, bexp, mbsum, log_init_z,
                                    alphaB, betaB, log_px);
    k_fbC  <<<93, 256, 0, stream>>>(ap1, bexp, alphaB, betaB, gam);
    k_py   <<<4096, 256, 0, stream>>>(x, means, gam, proj, term1, Gm, c2x,
                                      term0, xent, red);
    k_final<<<1, 256, 0, stream>>>(red, log_px, out);
}